// Round 7
// baseline (362.845 us; speedup 1.0000x reference)
//
#include <hip/hip_runtime.h>
#include <hip/hip_bf16.h>

typedef __attribute__((ext_vector_type(8))) short  short8;
typedef __attribute__((ext_vector_type(4))) short  short4v;
typedef __attribute__((ext_vector_type(4))) float  floatx4;
typedef unsigned short ushort_t;
typedef __attribute__((ext_vector_type(4))) unsigned short ushort4v;
typedef __attribute__((ext_vector_type(8))) unsigned short ushort8v;
typedef __attribute__((ext_vector_type(8))) _Float16 half8;   // for MFMA operands
typedef __attribute__((ext_vector_type(2))) __fp16   fp16x2;  // for cvt_pkrtz / fdot2

// ---------------- problem dims ----------------
constexpr int B_=4, C_=64, T_=8, X_=96, Y_=96;
constexpr int XY_  = X_*Y_;            // 9216
constexpr int TOT_ = B_*C_*T_*XY_;     // 18874368
constexpr float EPS_   = 1e-5f;
constexpr float SLOPE_ = 0.01f;
constexpr float QSC_   = 0.35355339059327373f;   // 1/sqrt(8)
constexpr float INV_BN_ = 1.0f/294912.0f;        // 1/(B*T*X*Y)
constexpr float INV_XY_ = 1.0f/9216.0f;

// hT padded layout: [bt][98_x][98_y][64] bf16; x-pad rows 0,97 and y-pad rows 0,97 zero.
constexpr int HT_XSTR_  = 98*64;                 // 6272 ushorts per padded-x row
constexpr int HT_BTSTR_ = 98*HT_XSTR_;           // 614656 ushorts per bt
constexpr size_t HT_BYTES_ = (size_t)32*HT_BTSTR_*2;  // 39337984

// ---------------- ws layout (bytes) ----------------
constexpr size_t OFF_HT   = 0;                         // bf16 padded hT
constexpr size_t OFF_X0   = HT_BYTES_ + 4096;          // +4KB pad (stage overrun of last slab)
constexpr size_t OFF_X2   = OFF_X0 + (size_t)TOT_*2;   // bf16 [n][t][c]
constexpr size_t OFF_WB   = OFF_X2 + (size_t)TOT_*2;   // bf16 conv0 B-frags 36864
constexpr size_t OFF_QP   = OFF_WB + 73728;            // f16 packed qkv B-frags 12288
constexpr size_t OFF_WP   = OFF_QP + 24576;            // f16 packed wo  B-frags 4096
constexpr size_t OFF_SUM0 = OFF_WP + 8192;
constexpr size_t OFF_SQ0  = OFF_SUM0 + 256;
constexpr size_t OFF_SUM1 = OFF_SQ0 + 256;
constexpr size_t OFF_SQ1  = OFF_SUM1 + 256;
constexpr size_t OFF_M    = OFF_SQ1 + 256;             // 2048 f32 [b][t][c]
constexpr size_t ZBYTES   = 1024 + 8192;               // zero from OFF_SUM0
constexpr size_t OFF_SC0  = OFF_M + 8192;
constexpr size_t OFF_SH0  = OFF_SC0 + 256;
constexpr size_t OFF_SC1  = OFF_SH0 + 256;
constexpr size_t OFF_SH1  = OFF_SC1 + 256;
constexpr size_t OFF_KERN = OFF_SH1 + 256;             // 800 f32 [b][t][25]

__device__ __forceinline__ float leaky_(float v){ return v >= 0.f ? v : SLOPE_*v; }
__device__ __forceinline__ float bf2f(ushort_t u){
    union { unsigned int i; float f; } c; c.i = ((unsigned int)u) << 16; return c.f;
}
__device__ __forceinline__ ushort_t f2bf(float f){
    __hip_bfloat16 b = __float2bfloat16(f);
    return *reinterpret_cast<ushort_t*>(&b);
}
__device__ __forceinline__ ushort_t f2h(float f){
    union { __fp16 h; ushort_t u; } cv; cv.h = (__fp16)f; return cv.u;
}
__device__ __forceinline__ float h2f(ushort_t u){
    union { __fp16 h; ushort_t u; } cv; cv.u = u; return (float)cv.h;
}
// async global -> LDS, 16B per lane; dest must be linear (base + lane*16 per wave)
__device__ __forceinline__ void gld16(const void* gp, void* lp){
    __builtin_amdgcn_global_load_lds(
        (const __attribute__((address_space(1))) void*)gp,
        (__attribute__((address_space(3))) void*)lp, 16, 0, 0);
}
union H8 { half8 h8; fp16x2 h2[4]; short8 s8; };

// ---------------- K0: MFMA B-fragment packing for conv0 / qkv / out_proj --------------
// wB stays bf16 (conv0); qP/wP are f16 (attn uses f16 MFMA + v_dot2_f32_f16).
__global__ void k_prep(const float* __restrict__ w0, const float* __restrict__ wqkv,
                       const float* __restrict__ wo,
                       ushort_t* __restrict__ wB, short* __restrict__ qP, short* __restrict__ wP){
    int i = blockIdx.x*256 + threadIdx.x;             // 53248 total
    if (i < 36864){
        int j = i & 7, lane = (i>>3) & 63, frag = i >> 9;
        int nt = frag & 3, kb = (frag>>2) & 1, tap = frag >> 3;
        int co = nt*16 + (lane & 15);
        int ci = kb*32 + (lane>>4)*8 + j;
        wB[i] = f2bf(w0[co*576 + ci*9 + tap]);
    } else if (i < 49152){
        int pos = i - 36864;
        int j = pos & 7, lane = (pos>>3)&63, kb = (pos>>9)&1, nt = pos>>10;
        int n = nt*16 + (lane&15);
        int c = kb*32 + (lane>>4)*8 + j;
        qP[pos] = (short)f2h(wqkv[n*64 + c]);
    } else if (i < 53248){
        int pos = i - 49152;
        int j = pos & 7, lane = (pos>>3)&63, kb = (pos>>9)&1, nt = pos>>10;
        int n = nt*16 + (lane&15);
        int c = kb*32 + (lane>>4)*8 + j;
        wP[pos] = (short)f2h(wo[n*64 + c]);
    }
}

// ---------------- K0b: transpose h -> padded hT [bt][98][98][64] ----------------------
__global__ __launch_bounds__(256) void k_hT(const float* __restrict__ h,
                                            ushort_t* __restrict__ hT){
    __shared__ float s[96*65];
    int xp = blockIdx.x, bt = blockIdx.y;            // xp: padded x index 0..97
    int b = bt >> 3, t = bt & 7;
    ushort_t* opb = hT + (size_t)(bt*98 + xp)*HT_XSTR_;
    if (xp == 0 || xp == 97){
        ushort8v z8 = {0,0,0,0,0,0,0,0};
        for (int i = threadIdx.x; i < 784; i += 256)
            *(ushort8v*)(opb + i*8) = z8;
        return;
    }
    int x = xp - 1;
    int c = threadIdx.x >> 2, yq = threadIdx.x & 3;
    const float* hp = h + ((size_t)(b*64 + c)*8 + t)*9216 + x*96 + yq*24;
    #pragma unroll
    for (int i=0;i<6;i++){
        float4 v = *(const float4*)(hp + i*4);
        int y = yq*24 + i*4;
        s[(y+0)*65 + c] = v.x;
        s[(y+1)*65 + c] = v.y;
        s[(y+2)*65 + c] = v.z;
        s[(y+3)*65 + c] = v.w;
    }
    __syncthreads();
    // zero y-pad rows 0 and 97
    if (threadIdx.x < 16){
        ushort8v z8 = {0,0,0,0,0,0,0,0};
        int r = (threadIdx.x < 8) ? 0 : 97;
        int o = (threadIdx.x & 7)*8;
        *(ushort8v*)(opb + r*64 + o) = z8;
    }
    ushort_t* op = opb + 64;                         // interior rows start at ypad=1
    int o0 = threadIdx.x*24;
    #pragma unroll
    for (int v8=0; v8<3; ++v8){
        ushort8v pk;
        #pragma unroll
        for (int j=0;j<8;j++){
            int o = o0 + v8*8 + j;
            pk[j] = f2bf(s[(o>>6)*65 + (o&63)]);
        }
        *(ushort8v*)(op + o0 + v8*8) = pk;
    }
}

// ---------------- K1: conv0, LDS-staged slab via global_load_lds + swizzled source ----
__global__ __launch_bounds__(256, 2) void k_conv0(const ushort_t* __restrict__ hT,
        const ushort_t* __restrict__ wB, const float* __restrict__ bias,
        ushort_t* __restrict__ x0, float* __restrict__ sum0, float* __restrict__ sq0){
    __shared__ __align__(16) char lds[77824];
    __shared__ float red[512];
    int tid = threadIdx.x;
    int lane = tid & 63, w = tid >> 6;
    int m = lane & 15, q = lane >> 4;
    int bt = blockIdx.y, b = bt >> 3, t = bt & 7;
    int bx = blockIdx.x;
    int xr = bx*4 + w;

    // stage: slab = padded-x rows [bx*4, bx*4+6) = one contiguous 75264B range (+pad)
    {
        const char* gsrc = (const char*)(hT + ((size_t)bt*98 + bx*4)*HT_XSTR_);
        #pragma unroll
        for (int it=0; it<19; ++it){
            int lin = (tid + it*256)*16;
            int src = lin ^ (((lin>>7)&7)<<4);       // involution on bits[6:4]
            gld16(gsrc + src, lds + lin);
        }
    }
    floatx4 acc[6][4];
    #pragma unroll
    for (int nt=0; nt<4; ++nt){
        float bv = bias[nt*16 + m];
        #pragma unroll
        for (int mt=0; mt<6; ++mt) acc[mt][nt] = {bv,bv,bv,bv};
    }
    __syncthreads();                                 // drains vmcnt before barrier

    #pragma unroll
    for (int tap=0; tap<9; ++tap){
        const int dx = tap/3, dy = tap%3;
        int rowg = (w + dx)*98 + m + dy;             // slab row (mt adds 16, mod-8 inv.)
        int swz  = (rowg & 7) << 4;
        #pragma unroll
        for (int kb=0; kb<2; ++kb){
            short8 bf[4];
            #pragma unroll
            for (int nt=0; nt<4; ++nt)
                bf[nt] = *(const short8*)(wB + ((tap*2+kb)*4 + nt)*512 + lane*8);
            int va = (rowg*128 + kb*64 + q*16) ^ swz;
            #pragma unroll
            for (int mt=0; mt<6; ++mt){
                short8 a = *(const short8*)(lds + va + mt*2048);   // unconditional
                #pragma unroll
                for (int nt=0; nt<4; ++nt)
                    acc[mt][nt] = __builtin_amdgcn_mfma_f32_16x16x32_bf16(a, bf[nt], acc[mt][nt], 0,0,0);
            }
        }
    }
    float ls[4] = {0,0,0,0}, lq[4] = {0,0,0,0};
    size_t outb = ((size_t)(b*9216 + xr*96)*8 + t)*64;
    #pragma unroll
    for (int mt=0; mt<6; ++mt){
        #pragma unroll
        for (int nt=0; nt<4; ++nt){
            #pragma unroll
            for (int r=0; r<4; ++r){
                float v = acc[mt][nt][r];
                ls[nt] += v; lq[nt] += v*v;
                int y = mt*16 + q*4 + r;
                x0[outb + (size_t)y*512 + nt*16 + m] = f2bf(v);
            }
        }
    }
    #pragma unroll
    for (int nt=0; nt<4; ++nt){
        ls[nt] += __shfl_xor(ls[nt], 16); ls[nt] += __shfl_xor(ls[nt], 32);
        lq[nt] += __shfl_xor(lq[nt], 16); lq[nt] += __shfl_xor(lq[nt], 32);
    }
    if (lane < 16){
        #pragma unroll
        for (int nt=0; nt<4; ++nt){
            red[w*64 + nt*16 + lane]       = ls[nt];
            red[256 + w*64 + nt*16 + lane] = lq[nt];
        }
    }
    __syncthreads();
    if (tid < 64){
        float a  = red[tid] + red[64+tid] + red[128+tid] + red[192+tid];
        float qq = red[256+tid] + red[320+tid] + red[384+tid] + red[448+tid];
        atomicAdd(&sum0[tid], a);
        atomicAdd(&sq0[tid], qq);
    }
}

// ---------------- finalize BN scale/shift ----------------
__global__ void k_fin(const float* __restrict__ sum, const float* __restrict__ sq,
                      const float* __restrict__ g, const float* __restrict__ be,
                      float* __restrict__ scale, float* __restrict__ shift, float inv_n){
    int c = threadIdx.x;
    float mu = sum[c]*inv_n;
    float var = sq[c]*inv_n - mu*mu;
    float rs = rsqrtf(var + EPS_);
    float sc = g[c]*rs;
    scale[c] = sc; shift[c] = be[c] - mu*sc;
}

// one (slab, head) attention stream: scores via v_dot2_f32_f16 on packed f16 (no unpack),
// softmax, PV via dot2 over kt-pairs against transposed V; om written to this lane's own
// swizzled q slot (the same slot this wave preloaded -> wave-private, race-free).
__device__ __forceinline__ void attn_f16(const ushort_t* qk, const ushort_t* vt,
        ushort_t* omdst, const fp16x2* qh, int p, int hh){
    float sv[8]; float mx = -1e30f;
    #pragma unroll
    for (int kt=0; kt<8; ++kt){
        union { short8 s; fp16x2 h[4]; } kv;
        kv.s = *(const short8*)(qk + (p*8+kt)*136 + 64 + ((hh^p)<<3));
        float s = 0.f;
        #pragma unroll
        for (int m=0;m<4;++m) s = __builtin_amdgcn_fdot2(qh[m], kv.h[m], s, false);
        sv[kt] = s; mx = fmaxf(mx, s);
    }
    float ssum = 0.f;
    #pragma unroll
    for (int kt=0;kt<8;++kt){ sv[kt] = __expf(sv[kt]-mx); ssum += sv[kt]; }
    float inv = 1.f/ssum;
    fp16x2 sp[4];
    #pragma unroll
    for (int m=0;m<4;++m) sp[m] = __builtin_amdgcn_cvt_pkrtz(sv[2*m]*inv, sv[2*m+1]*inv);
    union { short8 s; fp16x2 h[4]; } om;
    #pragma unroll
    for (int j2=0;j2<4;++j2){
        union { short8 s; fp16x2 h[4]; } v0, v1;
        v0.s = *(const short8*)(vt + (hh*8 + 2*j2    )*72 + p*8);
        v1.s = *(const short8*)(vt + (hh*8 + 2*j2 + 1)*72 + p*8);
        float o0 = 0.f, o1 = 0.f;
        #pragma unroll
        for (int m=0;m<4;++m){
            o0 = __builtin_amdgcn_fdot2(sp[m], v0.h[m], o0, false);
            o1 = __builtin_amdgcn_fdot2(sp[m], v1.h[m], o1, false);
        }
        om.h[j2] = __builtin_amdgcn_cvt_pkrtz(o0, o1);
    }
    *(short8*)omdst = om.s;
}

// ---------------- A12: BN0+leaky + MHA + residual -> x2 ; fused BN1 stats -------------
// R5 post-mortem: VALU cut (42->28%) moved time only 4% -> latency/fixed-cost bound, not
// VALU. v6: 768 blocks (3/CU, all resident, zero launch rounds), each loops 3 slab-pairs.
// Phase-4 x0 reloads AND next-iter phase-1 x0 loads issued at END of phase 1 (x0 is
// read-only -> safe to hoist across barriers manually); their latency hides under P2/P3.
// I-cache + barriers amortized 3x; stats atomics 1/3.
__global__ __launch_bounds__(256, 3) void k_attn(const ushort_t* __restrict__ x0,
        const float* __restrict__ sc0, const float* __restrict__ sh0,
        const short* __restrict__ qP, const float* __restrict__ bqkv,
        const short* __restrict__ wP, const float* __restrict__ bo,
        ushort_t* __restrict__ x2, float* __restrict__ sum1, float* __restrict__ sq1){
    __shared__ __align__(16) ushort_t smem[26624];   // 53248 B
    ushort_t* qkA = smem;                            // [64][136]
    ushort_t* vtA = smem + 8704;                     // [64][72]
    ushort_t* qkB = smem + 13312;
    ushort_t* vtB = smem + 22016;

    int tid = threadIdx.x;
    int b = blockIdx.z, xx = blockIdx.y, y0 = blockIdx.x*48;
    size_t base = ((size_t)(b*9216 + xx*96 + y0)) * 512;

    int lane = tid & 63, w = tid >> 6;
    int c16 = lane & 15, qd = lane >> 4;
    int tokA = w*16 + c16;

    // loop-invariant BN0 scale/shift for the A-frag channel slices
    float sca[8], sha[8], scb[8], shb[8];
    #pragma unroll
    for (int j=0;j<8;++j){
        sca[j] = sc0[qd*8 + j];      sha[j] = sh0[qd*8 + j];
        scb[j] = sc0[32 + qd*8 + j]; shb[j] = sh0[32 + qd*8 + j];
    }
    // P1 prefetch for iter 0
    const ushort_t* xr0 = x0 + base + (size_t)tokA*64;
    ushort8v pfA0 = *(const ushort8v*)(xr0 + qd*8);
    ushort8v pfA1 = *(const ushort8v*)(xr0 + 32 + qd*8);
    ushort8v pfB0 = *(const ushort8v*)(xr0 + 4096 + qd*8);
    ushort8v pfB1 = *(const ushort8v*)(xr0 + 4096 + 32 + qd*8);

    float ls[4] = {0,0,0,0}, lq[4] = {0,0,0,0};

    #pragma unroll 1
    for (int iter=0; iter<3; ++iter){
        size_t slabA = base + (size_t)iter*8192;
        size_t slabB = slabA + 4096;

        // ---- phase 1: BN0+leaky A-frags (f16) in regs; qkv GEMM (f16 MFMA) ----
        {
            float vA0[8], vA1[8], vB0[8], vB1[8];
            #pragma unroll
            for (int j=0;j<8;++j){
                vA0[j] = leaky_(bf2f(pfA0[j])*sca[j] + sha[j]);
                vA1[j] = leaky_(bf2f(pfA1[j])*scb[j] + shb[j]);
                vB0[j] = leaky_(bf2f(pfB0[j])*sca[j] + sha[j]);
                vB1[j] = leaky_(bf2f(pfB1[j])*scb[j] + shb[j]);
            }
            H8 a0A, a1A, a0B, a1B;
            #pragma unroll
            for (int m=0;m<4;++m){
                a0A.h2[m] = __builtin_amdgcn_cvt_pkrtz(vA0[2*m], vA0[2*m+1]);
                a1A.h2[m] = __builtin_amdgcn_cvt_pkrtz(vA1[2*m], vA1[2*m+1]);
                a0B.h2[m] = __builtin_amdgcn_cvt_pkrtz(vB0[2*m], vB0[2*m+1]);
                a1B.h2[m] = __builtin_amdgcn_cvt_pkrtz(vB1[2*m], vB1[2*m+1]);
            }
            #pragma unroll
            for (int nt=0; nt<12; ++nt){
                float bv = bqkv[nt*16 + c16];
                H8 b0, b1;
                b0.s8 = *(const short8*)(qP + (nt*2+0)*512 + lane*8);
                b1.s8 = *(const short8*)(qP + (nt*2+1)*512 + lane*8);
                floatx4 accA = {bv,bv,bv,bv};
                floatx4 accB = {bv,bv,bv,bv};
                accA = __builtin_amdgcn_mfma_f32_16x16x32_f16(a0A.h8, b0.h8, accA, 0, 0, 0);
                accB = __builtin_amdgcn_mfma_f32_16x16x32_f16(a0B.h8, b0.h8, accB, 0, 0, 0);
                accA = __builtin_amdgcn_mfma_f32_16x16x32_f16(a1A.h8, b1.h8, accA, 0, 0, 0);
                accB = __builtin_amdgcn_mfma_f32_16x16x32_f16(a1B.h8, b1.h8, accB, 0, 0, 0);
                if (nt < 4){
                    #pragma unroll
                    for (int r=0;r<4;++r){ accA[r]*=QSC_; accB[r]*=QSC_; }
                }
                if (nt < 8){
                    int cch = nt*2 + (c16>>3);           // chunk 0..15 (q then k)
                    int sub = c16 & 7;
                    #pragma unroll
                    for (int r=0;r<4;++r){
                        int row = w*16 + qd*4 + r;
                        int pp = row >> 3;
                        qkA[row*136 + ((cch^pp)<<3) + sub] = f2h(accA[r]);
                        qkB[row*136 + ((cch^pp)<<3) + sub] = f2h(accB[r]);
                    }
                } else {
                    int chv = (nt-8)*16 + c16;           // V channel, transposed store
                    union { fp16x2 h[2]; unsigned long long u; } pA, pB;
                    pA.h[0] = __builtin_amdgcn_cvt_pkrtz(accA[0], accA[1]);
                    pA.h[1] = __builtin_amdgcn_cvt_pkrtz(accA[2], accA[3]);
                    pB.h[0] = __builtin_amdgcn_cvt_pkrtz(accB[0], accB[1]);
                    pB.h[1] = __builtin_amdgcn_cvt_pkrtz(accB[2], accB[3]);
                    *(unsigned long long*)(vtA + chv*72 + (w*16 + qd*4)) = pA.u;
                    *(unsigned long long*)(vtB + chv*72 + (w*16 + qd*4)) = pB.u;
                }
            }
        }
        // ---- early-issue: phase-4 x0 reloads + next-iter phase-1 x0 loads (x0 is
        //      read-only; latency hides under P2/P3 across the barriers) ----
        ushort4v p4A[4], p4B[4];
        #pragma unroll
        for (int it=0; it<4; ++it){
            int e0 = (tid + it*256)*4;
            p4A[it] = *(const ushort4v*)(x0 + slabA + e0);
            p4B[it] = *(const ushort4v*)(x0 + slabB + e0);
        }
        if (iter < 2){
            const ushort_t* xrn = x0 + base + (size_t)(iter+1)*8192 + (size_t)tokA*64;
            pfA0 = *(const ushort8v*)(xrn + qd*8);
            pfA1 = *(const ushort8v*)(xrn + 32 + qd*8);
            pfB0 = *(const ushort8v*)(xrn + 4096 + qd*8);
            pfB1 = *(const ushort8v*)(xrn + 4096 + 32 + qd*8);
        }
        __syncthreads();

        // ---- phase 2: q preload (own swizzled slots), 4 independent attn streams ----
        {
            int tok = lane, p = tok >> 3;
            H8 qA0, qA1, qB0, qB1;
            qA0.s8 = *(const short8*)(qkA + tok*136 + ((w^p)<<3));
            qA1.s8 = *(const short8*)(qkA + tok*136 + (((w+4)^p)<<3));
            qB0.s8 = *(const short8*)(qkB + tok*136 + ((w^p)<<3));
            qB1.s8 = *(const short8*)(qkB + tok*136 + (((w+4)^p)<<3));
            attn_f16(qkA, vtA, qkA + tok*136 + ((w^p)<<3),     qA0.h2, p, w);
            attn_f16(qkB, vtB, qkB + tok*136 + ((w^p)<<3),     qB0.h2, p, w);
            attn_f16(qkA, vtA, qkA + tok*136 + (((w+4)^p)<<3), qA1.h2, p, w+4);
            attn_f16(qkB, vtB, qkB + tok*136 + (((w+4)^p)<<3), qB1.h2, p, w+4);
        }
        __syncthreads();

        // ---- phase 3: out_proj via f16 MFMA (+bo) -> oo (dead k region) ----
        {
            int row3 = w*16 + c16, p3 = row3 >> 3;
            H8 A0A, A1A, A0B, A1B;
            A0A.s8 = *(const short8*)(qkA + row3*136 + ((qd^p3)<<3));
            A1A.s8 = *(const short8*)(qkA + row3*136 + (((qd+4)^p3)<<3));
            A0B.s8 = *(const short8*)(qkB + row3*136 + ((qd^p3)<<3));
            A1B.s8 = *(const short8*)(qkB + row3*136 + (((qd+4)^p3)<<3));
            #pragma unroll
            for (int nt=0; nt<4; ++nt){
                float bv = bo[nt*16 + c16];
                H8 b0, b1;
                b0.s8 = *(const short8*)(wP + (nt*2+0)*512 + lane*8);
                b1.s8 = *(const short8*)(wP + (nt*2+1)*512 + lane*8);
                floatx4 accA = {bv,bv,bv,bv};
                floatx4 accB = {bv,bv,bv,bv};
                accA = __builtin_amdgcn_mfma_f32_16x16x32_f16(A0A.h8, b0.h8, accA, 0, 0, 0);
                accB = __builtin_amdgcn_mfma_f32_16x16x32_f16(A0B.h8, b0.h8, accB, 0, 0, 0);
                accA = __builtin_amdgcn_mfma_f32_16x16x32_f16(A1A.h8, b1.h8, accA, 0, 0, 0);
                accB = __builtin_amdgcn_mfma_f32_16x16x32_f16(A1B.h8, b1.h8, accB, 0, 0, 0);
                #pragma unroll
                for (int r=0;r<4;++r){
                    int row = w*16 + qd*4 + r;
                    qkA[row*136 + 64 + nt*16 + c16] = f2h(accA[r]);
                    qkB[row*136 + 64 + nt*16 + c16] = f2h(accB[r]);
                }
            }
        }
        __syncthreads();

        // ---- phase 4: residual + store x2 (x0 values already in regs) ; BN1 stats ----
        #pragma unroll
        for (int it=0; it<4; ++it){
            int g = tid + it*256;
            int e0 = g*4, tk = g>>4, c0 = e0 & 63;
            floatx4 sc = *(const floatx4*)(sc0 + c0);
            floatx4 sh = *(const floatx4*)(sh0 + c0);
            ushort4v xvA = p4A[it];
            ushort4v xvB = p4B[it];
            ushort4v ovA = *(const ushort4v*)(qkA + tk*136 + 64 + c0);
            ushort4v ovB = *(const ushort4v*)(qkB + tk*136 + 64 + c0);
            ushort4v stA, stB;
            #pragma unroll
            for (int j=0;j<4;++j){
                float x1A = leaky_(bf2f(xvA[j])*sc[j] + sh[j]);
                float x1B = leaky_(bf2f(xvB[j])*sc[j] + sh[j]);
                stA[j] = f2bf(x1A + h2f(ovA[j]));
                stB[j] = f2bf(x1B + h2f(ovB[j]));
                float vA = bf2f(stA[j]), vB = bf2f(stB[j]);
                ls[j] += vA + vB; lq[j] += vA*vA + vB*vB;
            }
            *(ushort4v*)(x2 + slabA + e0) = stA;
            *(ushort4v*)(x2 + slabB + e0) = stB;
        }
        __syncthreads();                             // LDS safe for next-iter P1 / red
    }

    float* red = (float*)smem;                  // 8192 B overlay (all LDS reads done)
    int slot = tid >> 4, c0s = (tid*4) & 63;
    #pragma unroll
    for (int j=0;j<4;++j){
        red[slot*64 + c0s + j]        = ls[j];
        red[1024 + slot*64 + c0s + j] = lq[j];
    }
    __syncthreads();
    if (tid < 128){
        int c = tid & 63;
        const float* base2 = red + (tid>>6)*1024 + c;
        float a = 0.f;
        #pragma unroll
        for (int s=0;s<16;++s) a += base2[s*64];
        atomicAdd((tid < 64) ? &sum1[c] : &sq1[c], a);
    }
}

// ---------------- m partial sums: sum over (x,y) of leaky(bn1(x2)) ----------------
// v6: vectorized ushort8 loads (wave reads 1KB contiguous) vs 192 scalar loads/thread.
__global__ __launch_bounds__(256) void k_m(const ushort_t* __restrict__ x2,
        const float* __restrict__ sc1, const float* __restrict__ sh1,
        float* __restrict__ msum){
    __shared__ float sred[2048];
    int c8 = threadIdx.x & 7, t = (threadIdx.x>>3)&7, tg = threadIdx.x >> 6;
    int b = blockIdx.y, chunk = blockIdx.x;
    float macc[8] = {0,0,0,0,0,0,0,0};
    float scv[8], shv[8];
    #pragma unroll
    for (int j=0;j<8;++j){ scv[j] = sc1[c8*8+j]; shv[j] = sh1[c8*8+j]; }
    int xy_end = chunk*96 + 96;
    for (int xy = chunk*96 + tg; xy < xy_end; xy += 4){
        ushort8v v8 = *(const ushort8v*)(x2 + ((size_t)(b*9216 + xy)*8 + t)*64 + c8*8);
        #pragma unroll
        for (int j=0;j<8;++j){
            float v = bf2f(v8[j]);
            macc[j] += leaky_(v*scv[j] + shv[j]);
        }
    }
    #pragma unroll
    for (int j=0;j<8;++j) sred[tg*512 + t*64 + c8*8 + j] = macc[j];
    __syncthreads();
    #pragma unroll
    for (int i=0;i<2;++i){
        int idx = threadIdx.x + i*256;               // (t,c) pair
        float a = sred[idx] + sred[512+idx] + sred[1024+idx] + sred[1536+idx];
        atomicAdd(&msum[b*512 + idx], a);
    }
}

// ---------------- kern[b][t][25] = conv1(m) ----------------
__global__ void k_kern(const float* __restrict__ msum, const float* __restrict__ w1,
                       const float* __restrict__ b1, float* __restrict__ kern){
    int tid = blockIdx.x*256 + threadIdx.x;
    if (tid >= 800) return;
    int o = tid % 25; int t = (tid/25) % 8; int b = tid/200;
    float s = b1[o];
    const float* mrow = msum + (b*8+t)*64;
    for (int c=0;c<64;c++) s += (mrow[c]*INV_XY_) * w1[o*64+c];
    kern[(b*8+t)*25 + o] = s;
}

// ---------------- final dynamic depthwise 5x5 conv: LDS-tiled, 1 block per (b,c,t) ----
__global__ __launch_bounds__(256) void k_final(const float* __restrict__ h,
        const float* __restrict__ kern, float* __restrict__ out){
    __shared__ float s[100*104];                     // rows x+2 (0..99), cols y+4 (stride 104)
    int bct = blockIdx.x;                            // = ((b*64+c)*8+t)
    int b = bct >> 9, t = bct & 7;
    int tid = threadIdx.x;
    const float* hp = h + (size_t)bct*9216;
    // zero border strips only (rows 0,1,98,99 full; cols 0-3 & 100-103 for rows 2..97)
    for (int i = tid; i < 1184; i += 256){
        int row, col;
        if (i < 416){ int r4 = i/104; row = (r4<2) ? r4 : 96 + r4; col = i - r4*104; }
        else { int j = i - 416; row = 2 + (j>>3); int k = j & 7; col = (k<4) ? k : 96 + k; }
        s[row*104 + col] = 0.f;
    }
    // interior fill: 2304 coalesced float4 loads -> aligned b128 LDS writes
    for (int i = tid; i < 2304; i += 256){
        int e = i*4; int xx = e/96, yy = e%96;       // yy%4==0
        float4 v = *(const float4*)(hp + e);
        *(float4*)(&s[(xx+2)*104 + yy + 4]) = v;
    }
    const float* kp = kern + ((size_t)(b*8+t))*25;
    float kv[25];
    #pragma unroll
    for (int i=0;i<25;i++) kv[i] = kp[i];
    __syncthreads();
    int tx = tid & 15, ty = tid >> 4;
    int x0 = ty*6, y0 = tx*6;
    float acc[6][6];
    #pragma unroll
    for (int i=0;i<6;i++)
        #pragma unroll
        for (int j=0;j<6;j++) acc[i][j] = 0.f;
    #pragma unroll
    for (int r=0; r<10; ++r){
        float row[10];
        const float* sp = &s[(x0+r)*104 + y0 + 2];   // LDS col of h[.][y0-2] is y0+2
        #pragma unroll
        for (int c=0;c<10;c++) row[c] = sp[c];
        #pragma unroll
        for (int orow=0; orow<6; ++orow){
            if (orow > r || orow < r-4) continue;    // static after unroll
            int dx = r - orow;
            #pragma unroll
            for (int dy=0; dy<5; ++dy){
                float wv = kv[dx*5+dy];
                #pragma unroll
                for (int oc=0; oc<6; ++oc)
                    acc[orow][oc] += wv * row[oc+dy];
            }
        }
    }
    float* op = out + (size_t)bct*9216 + x0*96 + y0;
    #pragma unroll
    for (int orow=0; orow<6; ++orow)
        #pragma unroll
        for (int oc=0; oc<6; ++oc)
            op[orow*96 + oc] = acc[orow][oc];
}

// ---------------- launch ----------------
extern "C" void kernel_launch(void* const* d_in, const int* in_sizes, int n_in,
                              void* d_out, int out_size, void* d_ws, size_t ws_size,
                              hipStream_t stream){
    const float* h    = (const float*)d_in[0];
    const float* w0   = (const float*)d_in[1];
    const float* cb0  = (const float*)d_in[2];
    const float* bn0g = (const float*)d_in[3];
    const float* bn0b = (const float*)d_in[4];
    const float* bn1g = (const float*)d_in[5];
    const float* bn1b = (const float*)d_in[6];
    const float* wqkv = (const float*)d_in[7];
    const float* bqkv = (const float*)d_in[8];
    const float* wo   = (const float*)d_in[9];
    const float* bo   = (const float*)d_in[10];
    const float* w1   = (const float*)d_in[11];
    const float* b1   = (const float*)d_in[12];

    char* ws = (char*)d_ws;
    ushort_t* hT  = (ushort_t*)(ws + OFF_HT);
    ushort_t* x0  = (ushort_t*)(ws + OFF_X0);
    ushort_t* x2  = (ushort_t*)(ws + OFF_X2);
    ushort_t* wB  = (ushort_t*)(ws + OFF_WB);
    short* qP     = (short*)(ws + OFF_QP);
    short* wP     = (short*)(ws + OFF_WP);
    float* sum0   = (float*)(ws + OFF_SUM0);
    float* sq0    = (float*)(ws + OFF_SQ0);
    float* sum1   = (float*)(ws + OFF_SUM1);
    float* sq1    = (float*)(ws + OFF_SQ1);
    float* msum   = (float*)(ws + OFF_M);
    float* sc0    = (float*)(ws + OFF_SC0);
    float* sh0    = (float*)(ws + OFF_SH0);
    float* sc1    = (float*)(ws + OFF_SC1);
    float* sh1    = (float*)(ws + OFF_SH1);
    float* kern   = (float*)(ws + OFF_KERN);
    float* outp   = (float*)d_out;

    (void)hipMemsetAsync(ws + OFF_SUM0, 0, ZBYTES, stream);
    k_prep  <<<208, 256, 0, stream>>>(w0, wqkv, wo, wB, qP, wP);
    k_hT    <<<dim3(98, 32), 256, 0, stream>>>(h, hT);
    k_conv0 <<<dim3(24, 32), 256, 0, stream>>>(hT, wB, cb0, x0, sum0, sq0);
    k_fin   <<<1, 64, 0, stream>>>(sum0, sq0, bn0g, bn0b, sc0, sh0, INV_BN_);
    k_attn  <<<dim3(2, 96, 4), 256, 0, stream>>>(x0, sc0, sh0, qP, bqkv, wP, bo, x2, sum1, sq1);
    k_fin   <<<1, 64, 0, stream>>>(sum1, sq1, bn1g, bn1b, sc1, sh1, INV_BN_);
    k_m     <<<dim3(96, 4), 256, 0, stream>>>(x2, sc1, sh1, msum);
    k_kern  <<<4, 256, 0, stream>>>(msum, w1, b1, kern);
    k_final <<<2048, 256, 0, stream>>>(h, kern, outp);
}

// Round 8
// 321.748 us; speedup vs baseline: 1.1277x; 1.1277x over previous
//
#include <hip/hip_runtime.h>
#include <hip/hip_bf16.h>

typedef __attribute__((ext_vector_type(8))) short  short8;
typedef __attribute__((ext_vector_type(4))) short  short4v;
typedef __attribute__((ext_vector_type(4))) float  floatx4;
typedef unsigned short ushort_t;
typedef __attribute__((ext_vector_type(4))) unsigned short ushort4v;
typedef __attribute__((ext_vector_type(8))) unsigned short ushort8v;
typedef __attribute__((ext_vector_type(8))) _Float16 half8;   // for MFMA operands
typedef __attribute__((ext_vector_type(2))) __fp16   fp16x2;  // for cvt_pkrtz / fdot2

// ---------------- problem dims ----------------
constexpr int B_=4, C_=64, T_=8, X_=96, Y_=96;
constexpr int XY_  = X_*Y_;            // 9216
constexpr int TOT_ = B_*C_*T_*XY_;     // 18874368
constexpr float EPS_   = 1e-5f;
constexpr float SLOPE_ = 0.01f;
constexpr float QSC_   = 0.35355339059327373f;   // 1/sqrt(8)
constexpr float INV_BN_ = 1.0f/294912.0f;        // 1/(B*T*X*Y)
constexpr float INV_XY_ = 1.0f/9216.0f;

// hT padded layout: [bt][98_x][98_y][64] bf16; x-pad rows 0,97 and y-pad rows 0,97 zero.
constexpr int HT_XSTR_  = 98*64;                 // 6272 ushorts per padded-x row
constexpr int HT_BTSTR_ = 98*HT_XSTR_;           // 614656 ushorts per bt
constexpr size_t HT_BYTES_ = (size_t)32*HT_BTSTR_*2;  // 39337984

// ---------------- ws layout (bytes) ----------------
constexpr size_t OFF_HT   = 0;                         // bf16 padded hT
constexpr size_t OFF_X0   = HT_BYTES_ + 4096;          // +4KB pad (stage overrun of last slab)
constexpr size_t OFF_X2   = OFF_X0 + (size_t)TOT_*2;   // bf16 [n][t][c]
constexpr size_t OFF_WB   = OFF_X2 + (size_t)TOT_*2;   // bf16 conv0 B-frags 36864
constexpr size_t OFF_QP   = OFF_WB + 73728;            // f16 packed qkv B-frags 12288
constexpr size_t OFF_WP   = OFF_QP + 24576;            // f16 packed wo  B-frags 4096
constexpr size_t OFF_SUM0 = OFF_WP + 8192;
constexpr size_t OFF_SQ0  = OFF_SUM0 + 256;
constexpr size_t OFF_SUM1 = OFF_SQ0 + 256;
constexpr size_t OFF_SQ1  = OFF_SUM1 + 256;
constexpr size_t OFF_M    = OFF_SQ1 + 256;             // 2048 f32 [b][t][c]
constexpr size_t ZBYTES   = 1024 + 8192;               // zero from OFF_SUM0
constexpr size_t OFF_SC0  = OFF_M + 8192;
constexpr size_t OFF_SH0  = OFF_SC0 + 256;
constexpr size_t OFF_SC1  = OFF_SH0 + 256;
constexpr size_t OFF_SH1  = OFF_SC1 + 256;
constexpr size_t OFF_KERN = OFF_SH1 + 256;             // 800 f32 [b][t][25]

__device__ __forceinline__ float leaky_(float v){ return v >= 0.f ? v : SLOPE_*v; }
__device__ __forceinline__ float bf2f(ushort_t u){
    union { unsigned int i; float f; } c; c.i = ((unsigned int)u) << 16; return c.f;
}
__device__ __forceinline__ ushort_t f2bf(float f){
    __hip_bfloat16 b = __float2bfloat16(f);
    return *reinterpret_cast<ushort_t*>(&b);
}
__device__ __forceinline__ ushort_t f2h(float f){
    union { __fp16 h; ushort_t u; } cv; cv.h = (__fp16)f; return cv.u;
}
__device__ __forceinline__ float h2f(ushort_t u){
    union { __fp16 h; ushort_t u; } cv; cv.u = u; return (float)cv.h;
}
// async global -> LDS, 16B per lane; dest must be linear (base + lane*16 per wave)
__device__ __forceinline__ void gld16(const void* gp, void* lp){
    __builtin_amdgcn_global_load_lds(
        (const __attribute__((address_space(1))) void*)gp,
        (__attribute__((address_space(3))) void*)lp, 16, 0, 0);
}
union H8 { half8 h8; fp16x2 h2[4]; short8 s8; };

// ---------------- K0: MFMA B-fragment packing for conv0 / qkv / out_proj --------------
// wB stays bf16 (conv0); qP/wP are f16 (attn uses f16 MFMA + v_dot2_f32_f16).
__global__ void k_prep(const float* __restrict__ w0, const float* __restrict__ wqkv,
                       const float* __restrict__ wo,
                       ushort_t* __restrict__ wB, short* __restrict__ qP, short* __restrict__ wP){
    int i = blockIdx.x*256 + threadIdx.x;             // 53248 total
    if (i < 36864){
        int j = i & 7, lane = (i>>3) & 63, frag = i >> 9;
        int nt = frag & 3, kb = (frag>>2) & 1, tap = frag >> 3;
        int co = nt*16 + (lane & 15);
        int ci = kb*32 + (lane>>4)*8 + j;
        wB[i] = f2bf(w0[co*576 + ci*9 + tap]);
    } else if (i < 49152){
        int pos = i - 36864;
        int j = pos & 7, lane = (pos>>3)&63, kb = (pos>>9)&1, nt = pos>>10;
        int n = nt*16 + (lane&15);
        int c = kb*32 + (lane>>4)*8 + j;
        qP[pos] = (short)f2h(wqkv[n*64 + c]);
    } else if (i < 53248){
        int pos = i - 49152;
        int j = pos & 7, lane = (pos>>3)&63, kb = (pos>>9)&1, nt = pos>>10;
        int n = nt*16 + (lane&15);
        int c = kb*32 + (lane>>4)*8 + j;
        wP[pos] = (short)f2h(wo[n*64 + c]);
    }
}

// ---------------- K0b: transpose h -> padded hT [bt][98][98][64] ----------------------
__global__ __launch_bounds__(256) void k_hT(const float* __restrict__ h,
                                            ushort_t* __restrict__ hT){
    __shared__ float s[96*65];
    int xp = blockIdx.x, bt = blockIdx.y;            // xp: padded x index 0..97
    int b = bt >> 3, t = bt & 7;
    ushort_t* opb = hT + (size_t)(bt*98 + xp)*HT_XSTR_;
    if (xp == 0 || xp == 97){
        ushort8v z8 = {0,0,0,0,0,0,0,0};
        for (int i = threadIdx.x; i < 784; i += 256)
            *(ushort8v*)(opb + i*8) = z8;
        return;
    }
    int x = xp - 1;
    int c = threadIdx.x >> 2, yq = threadIdx.x & 3;
    const float* hp = h + ((size_t)(b*64 + c)*8 + t)*9216 + x*96 + yq*24;
    #pragma unroll
    for (int i=0;i<6;i++){
        float4 v = *(const float4*)(hp + i*4);
        int y = yq*24 + i*4;
        s[(y+0)*65 + c] = v.x;
        s[(y+1)*65 + c] = v.y;
        s[(y+2)*65 + c] = v.z;
        s[(y+3)*65 + c] = v.w;
    }
    __syncthreads();
    // zero y-pad rows 0 and 97
    if (threadIdx.x < 16){
        ushort8v z8 = {0,0,0,0,0,0,0,0};
        int r = (threadIdx.x < 8) ? 0 : 97;
        int o = (threadIdx.x & 7)*8;
        *(ushort8v*)(opb + r*64 + o) = z8;
    }
    ushort_t* op = opb + 64;                         // interior rows start at ypad=1
    int o0 = threadIdx.x*24;
    #pragma unroll
    for (int v8=0; v8<3; ++v8){
        ushort8v pk;
        #pragma unroll
        for (int j=0;j<8;j++){
            int o = o0 + v8*8 + j;
            pk[j] = f2bf(s[(o>>6)*65 + (o&63)]);
        }
        *(ushort8v*)(op + o0 + v8*8) = pk;
    }
}

// ---------------- K1: conv0, LDS-staged slab via global_load_lds + swizzled source ----
__global__ __launch_bounds__(256, 2) void k_conv0(const ushort_t* __restrict__ hT,
        const ushort_t* __restrict__ wB, const float* __restrict__ bias,
        ushort_t* __restrict__ x0, float* __restrict__ sum0, float* __restrict__ sq0){
    __shared__ __align__(16) char lds[77824];
    __shared__ float red[512];
    int tid = threadIdx.x;
    int lane = tid & 63, w = tid >> 6;
    int m = lane & 15, q = lane >> 4;
    int bt = blockIdx.y, b = bt >> 3, t = bt & 7;
    int bx = blockIdx.x;
    int xr = bx*4 + w;

    // stage: slab = padded-x rows [bx*4, bx*4+6) = one contiguous 75264B range (+pad)
    {
        const char* gsrc = (const char*)(hT + ((size_t)bt*98 + bx*4)*HT_XSTR_);
        #pragma unroll
        for (int it=0; it<19; ++it){
            int lin = (tid + it*256)*16;
            int src = lin ^ (((lin>>7)&7)<<4);       // involution on bits[6:4]
            gld16(gsrc + src, lds + lin);
        }
    }
    floatx4 acc[6][4];
    #pragma unroll
    for (int nt=0; nt<4; ++nt){
        float bv = bias[nt*16 + m];
        #pragma unroll
        for (int mt=0; mt<6; ++mt) acc[mt][nt] = {bv,bv,bv,bv};
    }
    __syncthreads();                                 // drains vmcnt before barrier

    #pragma unroll
    for (int tap=0; tap<9; ++tap){
        const int dx = tap/3, dy = tap%3;
        int rowg = (w + dx)*98 + m + dy;             // slab row (mt adds 16, mod-8 inv.)
        int swz  = (rowg & 7) << 4;
        #pragma unroll
        for (int kb=0; kb<2; ++kb){
            short8 bf[4];
            #pragma unroll
            for (int nt=0; nt<4; ++nt)
                bf[nt] = *(const short8*)(wB + ((tap*2+kb)*4 + nt)*512 + lane*8);
            int va = (rowg*128 + kb*64 + q*16) ^ swz;
            #pragma unroll
            for (int mt=0; mt<6; ++mt){
                short8 a = *(const short8*)(lds + va + mt*2048);   // unconditional
                #pragma unroll
                for (int nt=0; nt<4; ++nt)
                    acc[mt][nt] = __builtin_amdgcn_mfma_f32_16x16x32_bf16(a, bf[nt], acc[mt][nt], 0,0,0);
            }
        }
    }
    float ls[4] = {0,0,0,0}, lq[4] = {0,0,0,0};
    size_t outb = ((size_t)(b*9216 + xr*96)*8 + t)*64;
    #pragma unroll
    for (int mt=0; mt<6; ++mt){
        #pragma unroll
        for (int nt=0; nt<4; ++nt){
            #pragma unroll
            for (int r=0; r<4; ++r){
                float v = acc[mt][nt][r];
                ls[nt] += v; lq[nt] += v*v;
                int y = mt*16 + q*4 + r;
                x0[outb + (size_t)y*512 + nt*16 + m] = f2bf(v);
            }
        }
    }
    #pragma unroll
    for (int nt=0; nt<4; ++nt){
        ls[nt] += __shfl_xor(ls[nt], 16); ls[nt] += __shfl_xor(ls[nt], 32);
        lq[nt] += __shfl_xor(lq[nt], 16); lq[nt] += __shfl_xor(lq[nt], 32);
    }
    if (lane < 16){
        #pragma unroll
        for (int nt=0; nt<4; ++nt){
            red[w*64 + nt*16 + lane]       = ls[nt];
            red[256 + w*64 + nt*16 + lane] = lq[nt];
        }
    }
    __syncthreads();
    if (tid < 64){
        float a  = red[tid] + red[64+tid] + red[128+tid] + red[192+tid];
        float qq = red[256+tid] + red[320+tid] + red[384+tid] + red[448+tid];
        atomicAdd(&sum0[tid], a);
        atomicAdd(&sq0[tid], qq);
    }
}

// ---------------- finalize BN scale/shift ----------------
__global__ void k_fin(const float* __restrict__ sum, const float* __restrict__ sq,
                      const float* __restrict__ g, const float* __restrict__ be,
                      float* __restrict__ scale, float* __restrict__ shift, float inv_n){
    int c = threadIdx.x;
    float mu = sum[c]*inv_n;
    float var = sq[c]*inv_n - mu*mu;
    float rs = rsqrtf(var + EPS_);
    float sc = g[c]*rs;
    scale[c] = sc; shift[c] = be[c] - mu*sc;
}

// one (slab, head) attention stream: scores via v_dot2_f32_f16 on packed f16 (no unpack),
// softmax, PV via dot2 over kt-pairs against transposed V; om written to this lane's own
// swizzled q slot (the same slot this wave preloaded -> wave-private, race-free).
__device__ __forceinline__ void attn_f16(const ushort_t* qk, const ushort_t* vt,
        ushort_t* omdst, const fp16x2* qh, int p, int hh){
    float sv[8]; float mx = -1e30f;
    #pragma unroll
    for (int kt=0; kt<8; ++kt){
        union { short8 s; fp16x2 h[4]; } kv;
        kv.s = *(const short8*)(qk + (p*8+kt)*136 + 64 + ((hh^p)<<3));
        float s = 0.f;
        #pragma unroll
        for (int m=0;m<4;++m) s = __builtin_amdgcn_fdot2(qh[m], kv.h[m], s, false);
        sv[kt] = s; mx = fmaxf(mx, s);
    }
    float ssum = 0.f;
    #pragma unroll
    for (int kt=0;kt<8;++kt){ sv[kt] = __expf(sv[kt]-mx); ssum += sv[kt]; }
    float inv = 1.f/ssum;
    fp16x2 sp[4];
    #pragma unroll
    for (int m=0;m<4;++m) sp[m] = __builtin_amdgcn_cvt_pkrtz(sv[2*m]*inv, sv[2*m+1]*inv);
    union { short8 s; fp16x2 h[4]; } om;
    #pragma unroll
    for (int j2=0;j2<4;++j2){
        union { short8 s; fp16x2 h[4]; } v0, v1;
        v0.s = *(const short8*)(vt + (hh*8 + 2*j2    )*72 + p*8);
        v1.s = *(const short8*)(vt + (hh*8 + 2*j2 + 1)*72 + p*8);
        float o0 = 0.f, o1 = 0.f;
        #pragma unroll
        for (int m=0;m<4;++m){
            o0 = __builtin_amdgcn_fdot2(sp[m], v0.h[m], o0, false);
            o1 = __builtin_amdgcn_fdot2(sp[m], v1.h[m], o1, false);
        }
        om.h[j2] = __builtin_amdgcn_cvt_pkrtz(o0, o1);
    }
    *(short8*)omdst = om.s;
}

// ---------------- A12: BN0+leaky + MHA + residual -> x2 ; fused BN1 stats -------------
// REVERTED to the proven R5 structure (76.4 µs). R6's persistent 3-iter loop blew up
// FETCH 18.8->226 MB / WRITE 38->165 MB (L3 locality destroyed) -> 114.9 µs. Mechanism
// not fully understood -> reverted per rigor discipline.
// f16 working set. Per slab: qk [64 tok][136 ush] (q | k | pad, 16B chunks swizzled
// pos=c^p), vT [64 ch][72 ush] (transposed V). 53248 B total, 3 blocks/CU.
__global__ __launch_bounds__(256, 3) void k_attn(const ushort_t* __restrict__ x0,
        const float* __restrict__ sc0, const float* __restrict__ sh0,
        const short* __restrict__ qP, const float* __restrict__ bqkv,
        const short* __restrict__ wP, const float* __restrict__ bo,
        ushort_t* __restrict__ x2, float* __restrict__ sum1, float* __restrict__ sq1){
    __shared__ __align__(16) ushort_t smem[26624];   // 53248 B
    ushort_t* qkA = smem;                            // [64][136]
    ushort_t* vtA = smem + 8704;                     // [64][72]
    ushort_t* qkB = smem + 13312;
    ushort_t* vtB = smem + 22016;

    int tid = threadIdx.x;
    int b = blockIdx.z, xx = blockIdx.y, y0 = blockIdx.x*16;
    size_t slabA = ((size_t)(b*9216 + xx*96 + y0)) * 512;
    size_t slabB = slabA + 4096;                     // +8 y rows

    int lane = tid & 63, w = tid >> 6;
    int c16 = lane & 15, qd = lane >> 4;

    // ---- phase 1: BN0+leaky A-frags (f16) in regs; qkv GEMM (f16 MFMA) both slabs ----
    {
        int tokA = w*16 + c16;
        const ushort_t* xrA = x0 + slabA + (size_t)tokA*64;
        const ushort_t* xrB = x0 + slabB + (size_t)tokA*64;
        ushort8v xaA = *(const ushort8v*)(xrA + qd*8);
        ushort8v xbA = *(const ushort8v*)(xrA + 32 + qd*8);
        ushort8v xaB = *(const ushort8v*)(xrB + qd*8);
        ushort8v xbB = *(const ushort8v*)(xrB + 32 + qd*8);
        float sca[8], sha[8], scb[8], shb[8];
        #pragma unroll
        for (int j=0;j<8;++j){
            sca[j] = sc0[qd*8 + j];      sha[j] = sh0[qd*8 + j];
            scb[j] = sc0[32 + qd*8 + j]; shb[j] = sh0[32 + qd*8 + j];
        }
        float vA0[8], vA1[8], vB0[8], vB1[8];
        #pragma unroll
        for (int j=0;j<8;++j){
            vA0[j] = leaky_(bf2f(xaA[j])*sca[j] + sha[j]);
            vA1[j] = leaky_(bf2f(xbA[j])*scb[j] + shb[j]);
            vB0[j] = leaky_(bf2f(xaB[j])*sca[j] + sha[j]);
            vB1[j] = leaky_(bf2f(xbB[j])*scb[j] + shb[j]);
        }
        H8 a0A, a1A, a0B, a1B;
        #pragma unroll
        for (int m=0;m<4;++m){
            a0A.h2[m] = __builtin_amdgcn_cvt_pkrtz(vA0[2*m], vA0[2*m+1]);
            a1A.h2[m] = __builtin_amdgcn_cvt_pkrtz(vA1[2*m], vA1[2*m+1]);
            a0B.h2[m] = __builtin_amdgcn_cvt_pkrtz(vB0[2*m], vB0[2*m+1]);
            a1B.h2[m] = __builtin_amdgcn_cvt_pkrtz(vB1[2*m], vB1[2*m+1]);
        }
        #pragma unroll
        for (int nt=0; nt<12; ++nt){
            float bv = bqkv[nt*16 + c16];
            H8 b0, b1;
            b0.s8 = *(const short8*)(qP + (nt*2+0)*512 + lane*8);
            b1.s8 = *(const short8*)(qP + (nt*2+1)*512 + lane*8);
            floatx4 accA = {bv,bv,bv,bv};
            floatx4 accB = {bv,bv,bv,bv};
            accA = __builtin_amdgcn_mfma_f32_16x16x32_f16(a0A.h8, b0.h8, accA, 0, 0, 0);
            accB = __builtin_amdgcn_mfma_f32_16x16x32_f16(a0B.h8, b0.h8, accB, 0, 0, 0);
            accA = __builtin_amdgcn_mfma_f32_16x16x32_f16(a1A.h8, b1.h8, accA, 0, 0, 0);
            accB = __builtin_amdgcn_mfma_f32_16x16x32_f16(a1B.h8, b1.h8, accB, 0, 0, 0);
            if (nt < 4){
                #pragma unroll
                for (int r=0;r<4;++r){ accA[r]*=QSC_; accB[r]*=QSC_; }
            }
            if (nt < 8){
                int cch = nt*2 + (c16>>3);           // chunk 0..15 (q then k)
                int sub = c16 & 7;
                #pragma unroll
                for (int r=0;r<4;++r){
                    int row = w*16 + qd*4 + r;
                    int pp = row >> 3;
                    qkA[row*136 + ((cch^pp)<<3) + sub] = f2h(accA[r]);
                    qkB[row*136 + ((cch^pp)<<3) + sub] = f2h(accB[r]);
                }
            } else {
                int chv = (nt-8)*16 + c16;           // V channel, transposed store
                union { fp16x2 h[2]; unsigned long long u; } pA, pB;
                pA.h[0] = __builtin_amdgcn_cvt_pkrtz(accA[0], accA[1]);
                pA.h[1] = __builtin_amdgcn_cvt_pkrtz(accA[2], accA[3]);
                pB.h[0] = __builtin_amdgcn_cvt_pkrtz(accB[0], accB[1]);
                pB.h[1] = __builtin_amdgcn_cvt_pkrtz(accB[2], accB[3]);
                *(unsigned long long*)(vtA + chv*72 + (w*16 + qd*4)) = pA.u;
                *(unsigned long long*)(vtB + chv*72 + (w*16 + qd*4)) = pB.u;
            }
        }
    }
    __syncthreads();

    // ---- phase 2: q preload (own swizzled slots), 4 independent attn streams;
    //      om overwrites exactly the slots this wave preloaded (wave-private) ----
    {
        int tok = lane, p = tok >> 3;
        H8 qA0, qA1, qB0, qB1;
        qA0.s8 = *(const short8*)(qkA + tok*136 + ((w^p)<<3));
        qA1.s8 = *(const short8*)(qkA + tok*136 + (((w+4)^p)<<3));
        qB0.s8 = *(const short8*)(qkB + tok*136 + ((w^p)<<3));
        qB1.s8 = *(const short8*)(qkB + tok*136 + (((w+4)^p)<<3));
        attn_f16(qkA, vtA, qkA + tok*136 + ((w^p)<<3),     qA0.h2, p, w);
        attn_f16(qkB, vtB, qkB + tok*136 + ((w^p)<<3),     qB0.h2, p, w);
        attn_f16(qkA, vtA, qkA + tok*136 + (((w+4)^p)<<3), qA1.h2, p, w+4);
        attn_f16(qkB, vtB, qkB + tok*136 + (((w+4)^p)<<3), qB1.h2, p, w+4);
    }
    __syncthreads();

    // ---- phase 3: out_proj via f16 MFMA (+bo) both slabs -> oo (dead k region) ----
    {
        int row3 = w*16 + c16, p3 = row3 >> 3;
        H8 A0A, A1A, A0B, A1B;
        A0A.s8 = *(const short8*)(qkA + row3*136 + ((qd^p3)<<3));
        A1A.s8 = *(const short8*)(qkA + row3*136 + (((qd+4)^p3)<<3));
        A0B.s8 = *(const short8*)(qkB + row3*136 + ((qd^p3)<<3));
        A1B.s8 = *(const short8*)(qkB + row3*136 + (((qd+4)^p3)<<3));
        #pragma unroll
        for (int nt=0; nt<4; ++nt){
            float bv = bo[nt*16 + c16];
            H8 b0, b1;
            b0.s8 = *(const short8*)(wP + (nt*2+0)*512 + lane*8);
            b1.s8 = *(const short8*)(wP + (nt*2+1)*512 + lane*8);
            floatx4 accA = {bv,bv,bv,bv};
            floatx4 accB = {bv,bv,bv,bv};
            accA = __builtin_amdgcn_mfma_f32_16x16x32_f16(A0A.h8, b0.h8, accA, 0, 0, 0);
            accB = __builtin_amdgcn_mfma_f32_16x16x32_f16(A0B.h8, b0.h8, accB, 0, 0, 0);
            accA = __builtin_amdgcn_mfma_f32_16x16x32_f16(A1A.h8, b1.h8, accA, 0, 0, 0);
            accB = __builtin_amdgcn_mfma_f32_16x16x32_f16(A1B.h8, b1.h8, accB, 0, 0, 0);
            #pragma unroll
            for (int r=0;r<4;++r){
                int row = w*16 + qd*4 + r;
                qkA[row*136 + 64 + nt*16 + c16] = f2h(accA[r]);
                qkB[row*136 + 64 + nt*16 + c16] = f2h(accB[r]);
            }
        }
    }
    __syncthreads();

    // ---- phase 4: residual + store x2 for both slabs ; fused BN1 partial stats ----
    float ls[4] = {0,0,0,0}, lq[4] = {0,0,0,0};
    #pragma unroll
    for (int it=0; it<4; ++it){
        int g = tid + it*256;
        int e0 = g*4, tk = g>>4, c0 = e0 & 63;
        floatx4 sc = *(const floatx4*)(sc0 + c0);
        floatx4 sh = *(const floatx4*)(sh0 + c0);
        ushort4v xvA = *(const ushort4v*)(x0 + slabA + e0);
        ushort4v xvB = *(const ushort4v*)(x0 + slabB + e0);
        ushort4v ovA = *(const ushort4v*)(qkA + tk*136 + 64 + c0);
        ushort4v ovB = *(const ushort4v*)(qkB + tk*136 + 64 + c0);
        ushort4v stA, stB;
        #pragma unroll
        for (int j=0;j<4;++j){
            float x1A = leaky_(bf2f(xvA[j])*sc[j] + sh[j]);
            float x1B = leaky_(bf2f(xvB[j])*sc[j] + sh[j]);
            stA[j] = f2bf(x1A + h2f(ovA[j]));
            stB[j] = f2bf(x1B + h2f(ovB[j]));
            float vA = bf2f(stA[j]), vB = bf2f(stB[j]);
            ls[j] += vA + vB; lq[j] += vA*vA + vB*vB;
        }
        *(ushort4v*)(x2 + slabA + e0) = stA;
        *(ushort4v*)(x2 + slabB + e0) = stB;
    }
    __syncthreads();
    float* red = (float*)smem;                  // 8192 B overlay (all LDS reads done)
    int slot = tid >> 4, c0s = (tid*4) & 63;
    #pragma unroll
    for (int j=0;j<4;++j){
        red[slot*64 + c0s + j]        = ls[j];
        red[1024 + slot*64 + c0s + j] = lq[j];
    }
    __syncthreads();
    if (tid < 128){
        int c = tid & 63;
        const float* base = red + (tid>>6)*1024 + c;
        float a = 0.f;
        #pragma unroll
        for (int s=0;s<16;++s) a += base[s*64];
        atomicAdd((tid < 64) ? &sum1[c] : &sq1[c], a);
    }
}

// ---------------- m partial sums: sum over (x,y) of leaky(bn1(x2)) ----------------
// vectorized ushort8 loads (wave reads 1KB contiguous).
__global__ __launch_bounds__(256) void k_m(const ushort_t* __restrict__ x2,
        const float* __restrict__ sc1, const float* __restrict__ sh1,
        float* __restrict__ msum){
    __shared__ float sred[2048];
    int c8 = threadIdx.x & 7, t = (threadIdx.x>>3)&7, tg = threadIdx.x >> 6;
    int b = blockIdx.y, chunk = blockIdx.x;
    float macc[8] = {0,0,0,0,0,0,0,0};
    float scv[8], shv[8];
    #pragma unroll
    for (int j=0;j<8;++j){ scv[j] = sc1[c8*8+j]; shv[j] = sh1[c8*8+j]; }
    int xy_end = chunk*96 + 96;
    for (int xy = chunk*96 + tg; xy < xy_end; xy += 4){
        ushort8v v8 = *(const ushort8v*)(x2 + ((size_t)(b*9216 + xy)*8 + t)*64 + c8*8);
        #pragma unroll
        for (int j=0;j<8;++j){
            float v = bf2f(v8[j]);
            macc[j] += leaky_(v*scv[j] + shv[j]);
        }
    }
    #pragma unroll
    for (int j=0;j<8;++j) sred[tg*512 + t*64 + c8*8 + j] = macc[j];
    __syncthreads();
    #pragma unroll
    for (int i=0;i<2;++i){
        int idx = threadIdx.x + i*256;               // (t,c) pair
        float a = sred[idx] + sred[512+idx] + sred[1024+idx] + sred[1536+idx];
        atomicAdd(&msum[b*512 + idx], a);
    }
}

// ---------------- kern[b][t][25] = conv1(m) ----------------
__global__ void k_kern(const float* __restrict__ msum, const float* __restrict__ w1,
                       const float* __restrict__ b1, float* __restrict__ kern){
    int tid = blockIdx.x*256 + threadIdx.x;
    if (tid >= 800) return;
    int o = tid % 25; int t = (tid/25) % 8; int b = tid/200;
    float s = b1[o];
    const float* mrow = msum + (b*8+t)*64;
    for (int c=0;c<64;c++) s += (mrow[c]*INV_XY_) * w1[o*64+c];
    kern[(b*8+t)*25 + o] = s;
}

// ---------------- final dynamic depthwise 5x5 conv: LDS-tiled, 1 block per (b,c,t) ----
__global__ __launch_bounds__(256) void k_final(const float* __restrict__ h,
        const float* __restrict__ kern, float* __restrict__ out){
    __shared__ float s[100*104];                     // rows x+2 (0..99), cols y+4 (stride 104)
    int bct = blockIdx.x;                            // = ((b*64+c)*8+t)
    int b = bct >> 9, t = bct & 7;
    int tid = threadIdx.x;
    const float* hp = h + (size_t)bct*9216;
    // zero border strips only (rows 0,1,98,99 full; cols 0-3 & 100-103 for rows 2..97)
    for (int i = tid; i < 1184; i += 256){
        int row, col;
        if (i < 416){ int r4 = i/104; row = (r4<2) ? r4 : 96 + r4; col = i - r4*104; }
        else { int j = i - 416; row = 2 + (j>>3); int k = j & 7; col = (k<4) ? k : 96 + k; }
        s[row*104 + col] = 0.f;
    }
    // interior fill: 2304 coalesced float4 loads -> aligned b128 LDS writes
    for (int i = tid; i < 2304; i += 256){
        int e = i*4; int xx = e/96, yy = e%96;       // yy%4==0
        float4 v = *(const float4*)(hp + e);
        *(float4*)(&s[(xx+2)*104 + yy + 4]) = v;
    }
    const float* kp = kern + ((size_t)(b*8+t))*25;
    float kv[25];
    #pragma unroll
    for (int i=0;i<25;i++) kv[i] = kp[i];
    __syncthreads();
    int tx = tid & 15, ty = tid >> 4;
    int x0 = ty*6, y0 = tx*6;
    float acc[6][6];
    #pragma unroll
    for (int i=0;i<6;i++)
        #pragma unroll
        for (int j=0;j<6;j++) acc[i][j] = 0.f;
    #pragma unroll
    for (int r=0; r<10; ++r){
        float row[10];
        const float* sp = &s[(x0+r)*104 + y0 + 2];   // LDS col of h[.][y0-2] is y0+2
        #pragma unroll
        for (int c=0;c<10;c++) row[c] = sp[c];
        #pragma unroll
        for (int orow=0; orow<6; ++orow){
            if (orow > r || orow < r-4) continue;    // static after unroll
            int dx = r - orow;
            #pragma unroll
            for (int dy=0; dy<5; ++dy){
                float wv = kv[dx*5+dy];
                #pragma unroll
                for (int oc=0; oc<6; ++oc)
                    acc[orow][oc] += wv * row[oc+dy];
            }
        }
    }
    float* op = out + (size_t)bct*9216 + x0*96 + y0;
    #pragma unroll
    for (int orow=0; orow<6; ++orow)
        #pragma unroll
        for (int oc=0; oc<6; ++oc)
            op[orow*96 + oc] = acc[orow][oc];
}

// ---------------- launch ----------------
extern "C" void kernel_launch(void* const* d_in, const int* in_sizes, int n_in,
                              void* d_out, int out_size, void* d_ws, size_t ws_size,
                              hipStream_t stream){
    const float* h    = (const float*)d_in[0];
    const float* w0   = (const float*)d_in[1];
    const float* cb0  = (const float*)d_in[2];
    const float* bn0g = (const float*)d_in[3];
    const float* bn0b = (const float*)d_in[4];
    const float* bn1g = (const float*)d_in[5];
    const float* bn1b = (const float*)d_in[6];
    const float* wqkv = (const float*)d_in[7];
    const float* bqkv = (const float*)d_in[8];
    const float* wo   = (const float*)d_in[9];
    const float* bo   = (const float*)d_in[10];
    const float* w1   = (const float*)d_in[11];
    const float* b1   = (const float*)d_in[12];

    char* ws = (char*)d_ws;
    ushort_t* hT  = (ushort_t*)(ws + OFF_HT);
    ushort_t* x0  = (ushort_t*)(ws + OFF_X0);
    ushort_t* x2  = (ushort_t*)(ws + OFF_X2);
    ushort_t* wB  = (ushort_t*)(ws + OFF_WB);
    short* qP     = (short*)(ws + OFF_QP);
    short* wP     = (short*)(ws + OFF_WP);
    float* sum0   = (float*)(ws + OFF_SUM0);
    float* sq0    = (float*)(ws + OFF_SQ0);
    float* sum1   = (float*)(ws + OFF_SUM1);
    float* sq1    = (float*)(ws + OFF_SQ1);
    float* msum   = (float*)(ws + OFF_M);
    float* sc0    = (float*)(ws + OFF_SC0);
    float* sh0    = (float*)(ws + OFF_SH0);
    float* sc1    = (float*)(ws + OFF_SC1);
    float* sh1    = (float*)(ws + OFF_SH1);
    float* kern   = (float*)(ws + OFF_KERN);
    float* outp   = (float*)d_out;

    (void)hipMemsetAsync(ws + OFF_SUM0, 0, ZBYTES, stream);
    k_prep  <<<208, 256, 0, stream>>>(w0, wqkv, wo, wB, qP, wP);
    k_hT    <<<dim3(98, 32), 256, 0, stream>>>(h, hT);
    k_conv0 <<<dim3(24, 32), 256, 0, stream>>>(hT, wB, cb0, x0, sum0, sq0);
    k_fin   <<<1, 64, 0, stream>>>(sum0, sq0, bn0g, bn0b, sc0, sh0, INV_BN_);
    k_attn  <<<dim3(6, 96, 4), 256, 0, stream>>>(x0, sc0, sh0, qP, bqkv, wP, bo, x2, sum1, sq1);
    k_fin   <<<1, 64, 0, stream>>>(sum1, sq1, bn1g, bn1b, sc1, sh1, INV_BN_);
    k_m     <<<dim3(96, 4), 256, 0, stream>>>(x2, sc1, sh1, msum);
    k_kern  <<<4, 256, 0, stream>>>(msum, w1, b1, kern);
    k_final <<<2048, 256, 0, stream>>>(h, kern, outp);
}

// Round 10
// 288.396 us; speedup vs baseline: 1.2582x; 1.1156x over previous
//
#include <hip/hip_runtime.h>
#include <hip/hip_bf16.h>

typedef __attribute__((ext_vector_type(8))) short  short8;
typedef __attribute__((ext_vector_type(4))) short  short4v;
typedef __attribute__((ext_vector_type(4))) float  floatx4;
typedef unsigned short ushort_t;
typedef __attribute__((ext_vector_type(4))) unsigned short ushort4v;
typedef __attribute__((ext_vector_type(8))) unsigned short ushort8v;
typedef __attribute__((ext_vector_type(8))) _Float16 half8;   // for MFMA operands
typedef __attribute__((ext_vector_type(2))) __fp16   fp16x2;  // for cvt_pkrtz / fdot2

// ---------------- problem dims ----------------
constexpr int B_=4, C_=64, T_=8, X_=96, Y_=96;
constexpr int XY_  = X_*Y_;            // 9216
constexpr int TOT_ = B_*C_*T_*XY_;     // 18874368
constexpr float EPS_   = 1e-5f;
constexpr float SLOPE_ = 0.01f;
constexpr float QSC_   = 0.35355339059327373f;   // 1/sqrt(8)
constexpr float INV_BN_ = 1.0f/294912.0f;        // 1/(B*T*X*Y)
constexpr float INV_XY_ = 1.0f/9216.0f;

// hT padded layout: [bt][98_x][98_y][64] bf16; x-pad rows 0,97 and y-pad rows 0,97 zero.
constexpr int HT_XSTR_  = 98*64;                 // 6272 ushorts per padded-x row
constexpr int HT_BTSTR_ = 98*HT_XSTR_;           // 614656 ushorts per bt
constexpr size_t HT_BYTES_ = (size_t)32*HT_BTSTR_*2;  // 39337984

// ---------------- ws layout (bytes) ----------------
constexpr size_t OFF_HT   = 0;                         // bf16 padded hT
constexpr size_t OFF_X0   = HT_BYTES_ + 4096;          // +4KB pad (stage overrun of last slab)
constexpr size_t OFF_X2   = OFF_X0 + (size_t)TOT_*2;   // bf16 [n][t][c]
constexpr size_t OFF_WB   = OFF_X2 + (size_t)TOT_*2;   // bf16 conv0 B-frags 36864
constexpr size_t OFF_QP   = OFF_WB + 73728;            // f16 packed qkv B-frags 12288
constexpr size_t OFF_WP   = OFF_QP + 24576;            // f16 packed wo  B-frags 4096
constexpr size_t OFF_M    = OFF_WP + 8192;             // 2048 f32 [b][t][c] (atomic, memset)
constexpr size_t OFF_SC0  = OFF_M + 8192;
constexpr size_t OFF_SH0  = OFF_SC0 + 256;
constexpr size_t OFF_SC1  = OFF_SH0 + 256;
constexpr size_t OFF_SH1  = OFF_SC1 + 256;
constexpr size_t OFF_KERN = OFF_SH1 + 256;             // 800 f32 [b][t][25]
constexpr size_t OFF_P0   = OFF_KERN + 3328;           // conv0 partials 768*128 f32
constexpr size_t OFF_P1   = OFF_P0 + 393216;           // attn partials 2304*128 f32

__device__ __forceinline__ float leaky_(float v){ return v >= 0.f ? v : SLOPE_*v; }
__device__ __forceinline__ float bf2f(ushort_t u){
    union { unsigned int i; float f; } c; c.i = ((unsigned int)u) << 16; return c.f;
}
__device__ __forceinline__ ushort_t f2bf(float f){
    __hip_bfloat16 b = __float2bfloat16(f);
    return *reinterpret_cast<ushort_t*>(&b);
}
__device__ __forceinline__ ushort_t f2h(float f){
    union { __fp16 h; ushort_t u; } cv; cv.h = (__fp16)f; return cv.u;
}
__device__ __forceinline__ float h2f(ushort_t u){
    union { __fp16 h; ushort_t u; } cv; cv.u = u; return (float)cv.h;
}
// async global -> LDS, 16B per lane; dest must be linear (base + lane*16 per wave)
__device__ __forceinline__ void gld16(const void* gp, void* lp){
    __builtin_amdgcn_global_load_lds(
        (const __attribute__((address_space(1))) void*)gp,
        (__attribute__((address_space(3))) void*)lp, 16, 0, 0);
}
union H8 { half8 h8; fp16x2 h2[4]; short8 s8; };

// ---------------- K0: MFMA B-fragment packing for conv0 / qkv / out_proj --------------
// wB stays bf16 (conv0); qP/wP are f16 (attn uses f16 MFMA + v_dot2_f32_f16).
__global__ void k_prep(const float* __restrict__ w0, const float* __restrict__ wqkv,
                       const float* __restrict__ wo,
                       ushort_t* __restrict__ wB, short* __restrict__ qP, short* __restrict__ wP){
    int i = blockIdx.x*256 + threadIdx.x;             // 53248 total
    if (i < 36864){
        int j = i & 7, lane = (i>>3) & 63, frag = i >> 9;
        int nt = frag & 3, kb = (frag>>2) & 1, tap = frag >> 3;
        int co = nt*16 + (lane & 15);
        int ci = kb*32 + (lane>>4)*8 + j;
        wB[i] = f2bf(w0[co*576 + ci*9 + tap]);
    } else if (i < 49152){
        int pos = i - 36864;
        int j = pos & 7, lane = (pos>>3)&63, kb = (pos>>9)&1, nt = pos>>10;
        int n = nt*16 + (lane&15);
        int c = kb*32 + (lane>>4)*8 + j;
        qP[pos] = (short)f2h(wqkv[n*64 + c]);
    } else if (i < 53248){
        int pos = i - 49152;
        int j = pos & 7, lane = (pos>>3)&63, kb = (pos>>9)&1, nt = pos>>10;
        int n = nt*16 + (lane&15);
        int c = kb*32 + (lane>>4)*8 + j;
        wP[pos] = (short)f2h(wo[n*64 + c]);
    }
}

// ---------------- K0b: transpose h -> padded hT [bt][98][98][64] ----------------------
__global__ __launch_bounds__(256) void k_hT(const float* __restrict__ h,
                                            ushort_t* __restrict__ hT){
    __shared__ float s[96*65];
    int xp = blockIdx.x, bt = blockIdx.y;            // xp: padded x index 0..97
    int b = bt >> 3, t = bt & 7;
    ushort_t* opb = hT + (size_t)(bt*98 + xp)*HT_XSTR_;
    if (xp == 0 || xp == 97){
        ushort8v z8 = {0,0,0,0,0,0,0,0};
        for (int i = threadIdx.x; i < 784; i += 256)
            *(ushort8v*)(opb + i*8) = z8;
        return;
    }
    int x = xp - 1;
    int c = threadIdx.x >> 2, yq = threadIdx.x & 3;
    const float* hp = h + ((size_t)(b*64 + c)*8 + t)*9216 + x*96 + yq*24;
    #pragma unroll
    for (int i=0;i<6;i++){
        float4 v = *(const float4*)(hp + i*4);
        int y = yq*24 + i*4;
        s[(y+0)*65 + c] = v.x;
        s[(y+1)*65 + c] = v.y;
        s[(y+2)*65 + c] = v.z;
        s[(y+3)*65 + c] = v.w;
    }
    __syncthreads();
    // zero y-pad rows 0 and 97
    if (threadIdx.x < 16){
        ushort8v z8 = {0,0,0,0,0,0,0,0};
        int r = (threadIdx.x < 8) ? 0 : 97;
        int o = (threadIdx.x & 7)*8;
        *(ushort8v*)(opb + r*64 + o) = z8;
    }
    ushort_t* op = opb + 64;                         // interior rows start at ypad=1
    int o0 = threadIdx.x*24;
    #pragma unroll
    for (int v8=0; v8<3; ++v8){
        ushort8v pk;
        #pragma unroll
        for (int j=0;j<8;j++){
            int o = o0 + v8*8 + j;
            pk[j] = f2bf(s[(o>>6)*65 + (o&63)]);
        }
        *(ushort8v*)(op + o0 + v8*8) = pk;
    }
}

// ---------------- K1: conv0, LDS-staged slab via global_load_lds + swizzled source ----
// BN0 stats: per-block partial STORES (coalesced 512B) instead of 98K same-address
// global atomics (R8 theory: atomic serialization ~27ns/addr was ~21us of this kernel).
__global__ __launch_bounds__(256, 2) void k_conv0(const ushort_t* __restrict__ hT,
        const ushort_t* __restrict__ wB, const float* __restrict__ bias,
        ushort_t* __restrict__ x0, float* __restrict__ part0){
    __shared__ __align__(16) char lds[77824];
    __shared__ float red[512];
    int tid = threadIdx.x;
    int lane = tid & 63, w = tid >> 6;
    int m = lane & 15, q = lane >> 4;
    int bt = blockIdx.y, b = bt >> 3, t = bt & 7;
    int bx = blockIdx.x;
    int xr = bx*4 + w;
    int bid = blockIdx.y*24 + blockIdx.x;

    // stage: slab = padded-x rows [bx*4, bx*4+6) = one contiguous 75264B range (+pad)
    {
        const char* gsrc = (const char*)(hT + ((size_t)bt*98 + bx*4)*HT_XSTR_);
        #pragma unroll
        for (int it=0; it<19; ++it){
            int lin = (tid + it*256)*16;
            int src = lin ^ (((lin>>7)&7)<<4);       // involution on bits[6:4]
            gld16(gsrc + src, lds + lin);
        }
    }
    floatx4 acc[6][4];
    #pragma unroll
    for (int nt=0; nt<4; ++nt){
        float bv = bias[nt*16 + m];
        #pragma unroll
        for (int mt=0; mt<6; ++mt) acc[mt][nt] = {bv,bv,bv,bv};
    }
    __syncthreads();                                 // drains vmcnt before barrier

    #pragma unroll
    for (int tap=0; tap<9; ++tap){
        const int dx = tap/3, dy = tap%3;
        int rowg = (w + dx)*98 + m + dy;             // slab row (mt adds 16, mod-8 inv.)
        int swz  = (rowg & 7) << 4;
        #pragma unroll
        for (int kb=0; kb<2; ++kb){
            short8 bf[4];
            #pragma unroll
            for (int nt=0; nt<4; ++nt)
                bf[nt] = *(const short8*)(wB + ((tap*2+kb)*4 + nt)*512 + lane*8);
            int va = (rowg*128 + kb*64 + q*16) ^ swz;
            #pragma unroll
            for (int mt=0; mt<6; ++mt){
                short8 a = *(const short8*)(lds + va + mt*2048);   // unconditional
                #pragma unroll
                for (int nt=0; nt<4; ++nt)
                    acc[mt][nt] = __builtin_amdgcn_mfma_f32_16x16x32_bf16(a, bf[nt], acc[mt][nt], 0,0,0);
            }
        }
    }
    float ls[4] = {0,0,0,0}, lq[4] = {0,0,0,0};
    size_t outb = ((size_t)(b*9216 + xr*96)*8 + t)*64;
    #pragma unroll
    for (int mt=0; mt<6; ++mt){
        #pragma unroll
        for (int nt=0; nt<4; ++nt){
            #pragma unroll
            for (int r=0; r<4; ++r){
                float v = acc[mt][nt][r];
                ls[nt] += v; lq[nt] += v*v;
                int y = mt*16 + q*4 + r;
                x0[outb + (size_t)y*512 + nt*16 + m] = f2bf(v);
            }
        }
    }
    #pragma unroll
    for (int nt=0; nt<4; ++nt){
        ls[nt] += __shfl_xor(ls[nt], 16); ls[nt] += __shfl_xor(ls[nt], 32);
        lq[nt] += __shfl_xor(lq[nt], 16); lq[nt] += __shfl_xor(lq[nt], 32);
    }
    if (lane < 16){
        #pragma unroll
        for (int nt=0; nt<4; ++nt){
            red[w*64 + nt*16 + lane]       = ls[nt];
            red[256 + w*64 + nt*16 + lane] = lq[nt];
        }
    }
    __syncthreads();
    if (tid < 64){
        float a  = red[tid] + red[64+tid] + red[128+tid] + red[192+tid];
        float qq = red[256+tid] + red[320+tid] + red[384+tid] + red[448+tid];
        part0[(size_t)bid*128 + tid]      = a;
        part0[(size_t)bid*128 + 64 + tid] = qq;
    }
}

// ---------------- reduce per-block partials -> BN scale/shift (replaces k_fin) -------
// grid: 64 blocks (one per channel) x 256 threads. part[bid][0..63]=sum, [64..127]=sq.
__global__ __launch_bounds__(256) void k_red(const float* __restrict__ part, int nblk,
        const float* __restrict__ g, const float* __restrict__ be,
        float* __restrict__ scale, float* __restrict__ shift, float inv_n){
    __shared__ float red[4];
    int c = blockIdx.x;
    int tid = threadIdx.x;
    int half = tid >> 7, l = tid & 127;
    float s = 0.f;
    for (int b = l; b < nblk; b += 128)
        s += part[(size_t)b*128 + half*64 + c];
    s += __shfl_down(s, 32); s += __shfl_down(s, 16); s += __shfl_down(s, 8);
    s += __shfl_down(s, 4);  s += __shfl_down(s, 2);  s += __shfl_down(s, 1);
    if ((tid & 63) == 0) red[tid >> 6] = s;
    __syncthreads();
    if (tid == 0){
        float sum = red[0] + red[1];
        float sq  = red[2] + red[3];
        float mu = sum*inv_n;
        float var = sq*inv_n - mu*mu;
        float rs = rsqrtf(var + EPS_);
        float sc = g[c]*rs;
        scale[c] = sc; shift[c] = be[c] - mu*sc;
    }
}

// one (slab, head) attention stream: scores via v_dot2_f32_f16 on packed f16 (no unpack),
// softmax, PV via dot2 over kt-pairs against transposed V; om written to this lane's own
// swizzled q slot (the same slot this wave preloaded -> wave-private, race-free).
__device__ __forceinline__ void attn_f16(const ushort_t* qk, const ushort_t* vt,
        ushort_t* omdst, const fp16x2* qh, int p, int hh){
    float sv[8]; float mx = -1e30f;
    #pragma unroll
    for (int kt=0; kt<8; ++kt){
        union { short8 s; fp16x2 h[4]; } kv;
        kv.s = *(const short8*)(qk + (p*8+kt)*136 + 64 + ((hh^p)<<3));
        float s = 0.f;
        #pragma unroll
        for (int m=0;m<4;++m) s = __builtin_amdgcn_fdot2(qh[m], kv.h[m], s, false);
        sv[kt] = s; mx = fmaxf(mx, s);
    }
    float ssum = 0.f;
    #pragma unroll
    for (int kt=0;kt<8;++kt){ sv[kt] = __expf(sv[kt]-mx); ssum += sv[kt]; }
    float inv = 1.f/ssum;
    fp16x2 sp[4];
    #pragma unroll
    for (int m=0;m<4;++m) sp[m] = __builtin_amdgcn_cvt_pkrtz(sv[2*m]*inv, sv[2*m+1]*inv);
    union { short8 s; fp16x2 h[4]; } om;
    #pragma unroll
    for (int j2=0;j2<4;++j2){
        union { short8 s; fp16x2 h[4]; } v0, v1;
        v0.s = *(const short8*)(vt + (hh*8 + 2*j2    )*72 + p*8);
        v1.s = *(const short8*)(vt + (hh*8 + 2*j2 + 1)*72 + p*8);
        float o0 = 0.f, o1 = 0.f;
        #pragma unroll
        for (int m=0;m<4;++m){
            o0 = __builtin_amdgcn_fdot2(sp[m], v0.h[m], o0, false);
            o1 = __builtin_amdgcn_fdot2(sp[m], v1.h[m], o1, false);
        }
        om.h[j2] = __builtin_amdgcn_cvt_pkrtz(o0, o1);
    }
    *(short8*)omdst = om.s;
}

// ---------------- A12: BN0+leaky + MHA + residual -> x2 ; fused BN1 stats -------------
// R5 structure; BN1 stats now per-block partial STORES instead of 295K same-address
// atomics (the R8 theory: 2304 serialized RMWs/address x ~27ns ~= 62us of this kernel).
__global__ __launch_bounds__(256, 3) void k_attn(const ushort_t* __restrict__ x0,
        const float* __restrict__ sc0, const float* __restrict__ sh0,
        const short* __restrict__ qP, const float* __restrict__ bqkv,
        const short* __restrict__ wP, const float* __restrict__ bo,
        ushort_t* __restrict__ x2, float* __restrict__ part1){
    __shared__ __align__(16) ushort_t smem[26624];   // 53248 B
    ushort_t* qkA = smem;                            // [64][136]
    ushort_t* vtA = smem + 8704;                     // [64][72]
    ushort_t* qkB = smem + 13312;
    ushort_t* vtB = smem + 22016;

    int tid = threadIdx.x;
    int b = blockIdx.z, xx = blockIdx.y, y0 = blockIdx.x*16;
    size_t slabA = ((size_t)(b*9216 + xx*96 + y0)) * 512;
    size_t slabB = slabA + 4096;                     // +8 y rows
    int bid = (blockIdx.z*96 + blockIdx.y)*6 + blockIdx.x;

    int lane = tid & 63, w = tid >> 6;
    int c16 = lane & 15, qd = lane >> 4;

    // ---- phase 1: BN0+leaky A-frags (f16) in regs; qkv GEMM (f16 MFMA) both slabs ----
    {
        int tokA = w*16 + c16;
        const ushort_t* xrA = x0 + slabA + (size_t)tokA*64;
        const ushort_t* xrB = x0 + slabB + (size_t)tokA*64;
        ushort8v xaA = *(const ushort8v*)(xrA + qd*8);
        ushort8v xbA = *(const ushort8v*)(xrA + 32 + qd*8);
        ushort8v xaB = *(const ushort8v*)(xrB + qd*8);
        ushort8v xbB = *(const ushort8v*)(xrB + 32 + qd*8);
        float sca[8], sha[8], scb[8], shb[8];
        #pragma unroll
        for (int j=0;j<8;++j){
            sca[j] = sc0[qd*8 + j];      sha[j] = sh0[qd*8 + j];
            scb[j] = sc0[32 + qd*8 + j]; shb[j] = sh0[32 + qd*8 + j];
        }
        float vA0[8], vA1[8], vB0[8], vB1[8];
        #pragma unroll
        for (int j=0;j<8;++j){
            vA0[j] = leaky_(bf2f(xaA[j])*sca[j] + sha[j]);
            vA1[j] = leaky_(bf2f(xbA[j])*scb[j] + shb[j]);
            vB0[j] = leaky_(bf2f(xaB[j])*sca[j] + sha[j]);
            vB1[j] = leaky_(bf2f(xbB[j])*scb[j] + shb[j]);
        }
        H8 a0A, a1A, a0B, a1B;
        #pragma unroll
        for (int m=0;m<4;++m){
            a0A.h2[m] = __builtin_amdgcn_cvt_pkrtz(vA0[2*m], vA0[2*m+1]);
            a1A.h2[m] = __builtin_amdgcn_cvt_pkrtz(vA1[2*m], vA1[2*m+1]);
            a0B.h2[m] = __builtin_amdgcn_cvt_pkrtz(vB0[2*m], vB0[2*m+1]);
            a1B.h2[m] = __builtin_amdgcn_cvt_pkrtz(vB1[2*m], vB1[2*m+1]);
        }
        #pragma unroll
        for (int nt=0; nt<12; ++nt){
            float bv = bqkv[nt*16 + c16];
            H8 b0, b1;
            b0.s8 = *(const short8*)(qP + (nt*2+0)*512 + lane*8);
            b1.s8 = *(const short8*)(qP + (nt*2+1)*512 + lane*8);
            floatx4 accA = {bv,bv,bv,bv};
            floatx4 accB = {bv,bv,bv,bv};
            accA = __builtin_amdgcn_mfma_f32_16x16x32_f16(a0A.h8, b0.h8, accA, 0, 0, 0);
            accB = __builtin_amdgcn_mfma_f32_16x16x32_f16(a0B.h8, b0.h8, accB, 0, 0, 0);
            accA = __builtin_amdgcn_mfma_f32_16x16x32_f16(a1A.h8, b1.h8, accA, 0, 0, 0);
            accB = __builtin_amdgcn_mfma_f32_16x16x32_f16(a1B.h8, b1.h8, accB, 0, 0, 0);
            if (nt < 4){
                #pragma unroll
                for (int r=0;r<4;++r){ accA[r]*=QSC_; accB[r]*=QSC_; }
            }
            if (nt < 8){
                int cch = nt*2 + (c16>>3);           // chunk 0..15 (q then k)
                int sub = c16 & 7;
                #pragma unroll
                for (int r=0;r<4;++r){
                    int row = w*16 + qd*4 + r;
                    int pp = row >> 3;
                    qkA[row*136 + ((cch^pp)<<3) + sub] = f2h(accA[r]);
                    qkB[row*136 + ((cch^pp)<<3) + sub] = f2h(accB[r]);
                }
            } else {
                int chv = (nt-8)*16 + c16;           // V channel, transposed store
                union { fp16x2 h[2]; unsigned long long u; } pA, pB;
                pA.h[0] = __builtin_amdgcn_cvt_pkrtz(accA[0], accA[1]);
                pA.h[1] = __builtin_amdgcn_cvt_pkrtz(accA[2], accA[3]);
                pB.h[0] = __builtin_amdgcn_cvt_pkrtz(accB[0], accB[1]);
                pB.h[1] = __builtin_amdgcn_cvt_pkrtz(accB[2], accB[3]);
                *(unsigned long long*)(vtA + chv*72 + (w*16 + qd*4)) = pA.u;
                *(unsigned long long*)(vtB + chv*72 + (w*16 + qd*4)) = pB.u;
            }
        }
    }
    __syncthreads();

    // ---- phase 2: q preload (own swizzled slots), 4 independent attn streams;
    //      om overwrites exactly the slots this wave preloaded (wave-private) ----
    {
        int tok = lane, p = tok >> 3;
        H8 qA0, qA1, qB0, qB1;
        qA0.s8 = *(const short8*)(qkA + tok*136 + ((w^p)<<3));
        qA1.s8 = *(const short8*)(qkA + tok*136 + (((w+4)^p)<<3));
        qB0.s8 = *(const short8*)(qkB + tok*136 + ((w^p)<<3));
        qB1.s8 = *(const short8*)(qkB + tok*136 + (((w+4)^p)<<3));
        attn_f16(qkA, vtA, qkA + tok*136 + ((w^p)<<3),     qA0.h2, p, w);
        attn_f16(qkB, vtB, qkB + tok*136 + ((w^p)<<3),     qB0.h2, p, w);
        attn_f16(qkA, vtA, qkA + tok*136 + (((w+4)^p)<<3), qA1.h2, p, w+4);
        attn_f16(qkB, vtB, qkB + tok*136 + (((w+4)^p)<<3), qB1.h2, p, w+4);
    }
    __syncthreads();

    // ---- phase 3: out_proj via f16 MFMA (+bo) both slabs -> oo (dead k region) ----
    {
        int row3 = w*16 + c16, p3 = row3 >> 3;
        H8 A0A, A1A, A0B, A1B;
        A0A.s8 = *(const short8*)(qkA + row3*136 + ((qd^p3)<<3));
        A1A.s8 = *(const short8*)(qkA + row3*136 + (((qd+4)^p3)<<3));
        A0B.s8 = *(const short8*)(qkB + row3*136 + ((qd^p3)<<3));
        A1B.s8 = *(const short8*)(qkB + row3*136 + (((qd+4)^p3)<<3));
        #pragma unroll
        for (int nt=0; nt<4; ++nt){
            float bv = bo[nt*16 + c16];
            H8 b0, b1;
            b0.s8 = *(const short8*)(wP + (nt*2+0)*512 + lane*8);
            b1.s8 = *(const short8*)(wP + (nt*2+1)*512 + lane*8);
            floatx4 accA = {bv,bv,bv,bv};
            floatx4 accB = {bv,bv,bv,bv};
            accA = __builtin_amdgcn_mfma_f32_16x16x32_f16(A0A.h8, b0.h8, accA, 0, 0, 0);
            accB = __builtin_amdgcn_mfma_f32_16x16x32_f16(A0B.h8, b0.h8, accB, 0, 0, 0);
            accA = __builtin_amdgcn_mfma_f32_16x16x32_f16(A1A.h8, b1.h8, accA, 0, 0, 0);
            accB = __builtin_amdgcn_mfma_f32_16x16x32_f16(A1B.h8, b1.h8, accB, 0, 0, 0);
            #pragma unroll
            for (int r=0;r<4;++r){
                int row = w*16 + qd*4 + r;
                qkA[row*136 + 64 + nt*16 + c16] = f2h(accA[r]);
                qkB[row*136 + 64 + nt*16 + c16] = f2h(accB[r]);
            }
        }
    }
    __syncthreads();

    // ---- phase 4: residual + store x2 for both slabs ; fused BN1 partial stats ----
    float ls[4] = {0,0,0,0}, lq[4] = {0,0,0,0};
    #pragma unroll
    for (int it=0; it<4; ++it){
        int g = tid + it*256;
        int e0 = g*4, tk = g>>4, c0 = e0 & 63;
        floatx4 sc = *(const floatx4*)(sc0 + c0);
        floatx4 sh = *(const floatx4*)(sh0 + c0);
        ushort4v xvA = *(const ushort4v*)(x0 + slabA + e0);
        ushort4v xvB = *(const ushort4v*)(x0 + slabB + e0);
        ushort4v ovA = *(const ushort4v*)(qkA + tk*136 + 64 + c0);
        ushort4v ovB = *(const ushort4v*)(qkB + tk*136 + 64 + c0);
        ushort4v stA, stB;
        #pragma unroll
        for (int j=0;j<4;++j){
            float x1A = leaky_(bf2f(xvA[j])*sc[j] + sh[j]);
            float x1B = leaky_(bf2f(xvB[j])*sc[j] + sh[j]);
            stA[j] = f2bf(x1A + h2f(ovA[j]));
            stB[j] = f2bf(x1B + h2f(ovB[j]));
            float vA = bf2f(stA[j]), vB = bf2f(stB[j]);
            ls[j] += vA + vB; lq[j] += vA*vA + vB*vB;
        }
        *(ushort4v*)(x2 + slabA + e0) = stA;
        *(ushort4v*)(x2 + slabB + e0) = stB;
    }
    __syncthreads();
    float* red = (float*)smem;                  // 8192 B overlay (all LDS reads done)
    int slot = tid >> 4, c0s = (tid*4) & 63;
    #pragma unroll
    for (int j=0;j<4;++j){
        red[slot*64 + c0s + j]        = ls[j];
        red[1024 + slot*64 + c0s + j] = lq[j];
    }
    __syncthreads();
    if (tid < 128){
        int c = tid & 63;
        const float* base = red + (tid>>6)*1024 + c;
        float a = 0.f;
        #pragma unroll
        for (int s=0;s<16;++s) a += base[s*64];
        part1[(size_t)bid*128 + tid] = a;       // tid<64: sum[c]; tid>=64: sq[c]
    }
}

// ---------------- m partial sums: sum over (x,y) of leaky(bn1(x2)) ----------------
// vectorized ushort8 loads (wave reads 1KB contiguous).
__global__ __launch_bounds__(256) void k_m(const ushort_t* __restrict__ x2,
        const float* __restrict__ sc1, const float* __restrict__ sh1,
        float* __restrict__ msum){
    __shared__ float sred[2048];
    int c8 = threadIdx.x & 7, t = (threadIdx.x>>3)&7, tg = threadIdx.x >> 6;
    int b = blockIdx.y, chunk = blockIdx.x;
    float macc[8] = {0,0,0,0,0,0,0,0};
    float scv[8], shv[8];
    #pragma unroll
    for (int j=0;j<8;++j){ scv[j] = sc1[c8*8+j]; shv[j] = sh1[c8*8+j]; }
    int xy_end = chunk*96 + 96;
    for (int xy = chunk*96 + tg; xy < xy_end; xy += 4){
        ushort8v v8 = *(const ushort8v*)(x2 + ((size_t)(b*9216 + xy)*8 + t)*64 + c8*8);
        #pragma unroll
        for (int j=0;j<8;++j){
            float v = bf2f(v8[j]);
            macc[j] += leaky_(v*scv[j] + shv[j]);
        }
    }
    #pragma unroll
    for (int j=0;j<8;++j) sred[tg*512 + t*64 + c8*8 + j] = macc[j];
    __syncthreads();
    #pragma unroll
    for (int i=0;i<2;++i){
        int idx = threadIdx.x + i*256;               // (t,c) pair
        float a = sred[idx] + sred[512+idx] + sred[1024+idx] + sred[1536+idx];
        atomicAdd(&msum[b*512 + idx], a);
    }
}

// ---------------- kern[b][t][25] = conv1(m) ----------------
__global__ void k_kern(const float* __restrict__ msum, const float* __restrict__ w1,
                       const float* __restrict__ b1, float* __restrict__ kern){
    int tid = blockIdx.x*256 + threadIdx.x;
    if (tid >= 800) return;
    int o = tid % 25; int t = (tid/25) % 8; int b = tid/200;
    float s = b1[o];
    const float* mrow = msum + (b*8+t)*64;
    for (int c=0;c<64;c++) s += (mrow[c]*INV_XY_) * w1[o*64+c];
    kern[(b*8+t)*25 + o] = s;
}

// ---------------- final dynamic depthwise 5x5 conv: LDS-tiled, 1 block per (b,c,t) ----
__global__ __launch_bounds__(256) void k_final(const float* __restrict__ h,
        const float* __restrict__ kern, float* __restrict__ out){
    __shared__ float s[100*104];                     // rows x+2 (0..99), cols y+4 (stride 104)
    int bct = blockIdx.x;                            // = ((b*64+c)*8+t)
    int b = bct >> 9, t = bct & 7;
    int tid = threadIdx.x;
    const float* hp = h + (size_t)bct*9216;
    // zero border strips only (rows 0,1,98,99 full; cols 0-3 & 100-103 for rows 2..97)
    for (int i = tid; i < 1184; i += 256){
        int row, col;
        if (i < 416){ int r4 = i/104; row = (r4<2) ? r4 : 96 + r4; col = i - r4*104; }
        else { int j = i - 416; row = 2 + (j>>3); int k = j & 7; col = (k<4) ? k : 96 + k; }
        s[row*104 + col] = 0.f;
    }
    // interior fill: 2304 coalesced float4 loads -> aligned b128 LDS writes
    for (int i = tid; i < 2304; i += 256){
        int e = i*4; int xx = e/96, yy = e%96;       // yy%4==0
        float4 v = *(const float4*)(hp + e);
        *(float4*)(&s[(xx+2)*104 + yy + 4]) = v;
    }
    const float* kp = kern + ((size_t)(b*8+t))*25;
    float kv[25];
    #pragma unroll
    for (int i=0;i<25;i++) kv[i] = kp[i];
    __syncthreads();
    int tx = tid & 15, ty = tid >> 4;
    int x0 = ty*6, y0 = tx*6;
    float acc[6][6];
    #pragma unroll
    for (int i=0;i<6;i++)
        #pragma unroll
        for (int j=0;j<6;j++) acc[i][j] = 0.f;
    #pragma unroll
    for (int r=0; r<10; ++r){
        float row[10];
        const float* sp = &s[(x0+r)*104 + y0 + 2];   // LDS col of h[.][y0-2] is y0+2
        #pragma unroll
        for (int c=0;c<10;c++) row[c] = sp[c];
        #pragma unroll
        for (int orow=0; orow<6; ++orow){
            if (orow > r || orow < r-4) continue;    // static after unroll
            int dx = r - orow;
            #pragma unroll
            for (int dy=0; dy<5; ++dy){
                float wv = kv[dx*5+dy];
                #pragma unroll
                for (int oc=0; oc<6; ++oc)
                    acc[orow][oc] += wv * row[oc+dy];
            }
        }
    }
    float* op = out + (size_t)bct*9216 + x0*96 + y0;
    #pragma unroll
    for (int orow=0; orow<6; ++orow)
        #pragma unroll
        for (int oc=0; oc<6; ++oc)
            op[orow*96 + oc] = acc[orow][oc];
}

// ---------------- launch ----------------
extern "C" void kernel_launch(void* const* d_in, const int* in_sizes, int n_in,
                              void* d_out, int out_size, void* d_ws, size_t ws_size,
                              hipStream_t stream){
    const float* h    = (const float*)d_in[0];
    const float* w0   = (const float*)d_in[1];
    const float* cb0  = (const float*)d_in[2];
    const float* bn0g = (const float*)d_in[3];
    const float* bn0b = (const float*)d_in[4];
    const float* bn1g = (const float*)d_in[5];
    const float* bn1b = (const float*)d_in[6];
    const float* wqkv = (const float*)d_in[7];
    const float* bqkv = (const float*)d_in[8];
    const float* wo   = (const float*)d_in[9];
    const float* bo   = (const float*)d_in[10];
    const float* w1   = (const float*)d_in[11];
    const float* b1   = (const float*)d_in[12];

    char* ws = (char*)d_ws;
    ushort_t* hT  = (ushort_t*)(ws + OFF_HT);
    ushort_t* x0  = (ushort_t*)(ws + OFF_X0);
    ushort_t* x2  = (ushort_t*)(ws + OFF_X2);
    ushort_t* wB  = (ushort_t*)(ws + OFF_WB);
    short* qP     = (short*)(ws + OFF_QP);
    short* wP     = (short*)(ws + OFF_WP);
    float* msum   = (float*)(ws + OFF_M);
    float* sc0    = (float*)(ws + OFF_SC0);
    float* sh0    = (float*)(ws + OFF_SH0);
    float* sc1    = (float*)(ws + OFF_SC1);
    float* sh1    = (float*)(ws + OFF_SH1);
    float* kern   = (float*)(ws + OFF_KERN);
    float* part0  = (float*)(ws + OFF_P0);
    float* part1  = (float*)(ws + OFF_P1);
    float* outp   = (float*)d_out;

    (void)hipMemsetAsync(ws + OFF_M, 0, 8192, stream);   // msum only (atomic target)
    k_prep  <<<208, 256, 0, stream>>>(w0, wqkv, wo, wB, qP, wP);
    k_hT    <<<dim3(98, 32), 256, 0, stream>>>(h, hT);
    k_conv0 <<<dim3(24, 32), 256, 0, stream>>>(hT, wB, cb0, x0, part0);
    k_red   <<<64, 256, 0, stream>>>(part0, 768, bn0g, bn0b, sc0, sh0, INV_BN_);
    k_attn  <<<dim3(6, 96, 4), 256, 0, stream>>>(x0, sc0, sh0, qP, bqkv, wP, bo, x2, part1);
    k_red   <<<64, 256, 0, stream>>>(part1, 2304, bn1g, bn1b, sc1, sh1, INV_BN_);
    k_m     <<<dim3(96, 4), 256, 0, stream>>>(x2, sc1, sh1, msum);
    k_kern  <<<4, 256, 0, stream>>>(msum, w1, b1, kern);
    k_final <<<2048, 256, 0, stream>>>(h, kern, outp);
}